// Round 17
// baseline (5185.846 us; speedup 1.0000x reference)
//
#include <hip/hip_runtime.h>
#include <hip/hip_bf16.h>
#include <hip/hip_fp16.h>
#include <math.h>

// ---------------------------------------------------------------------------
// R17: dispatch fusion. All 7 kRedPart launches + kFinal folded away:
//  - each stat-producing kernel reduces its own partials in its LAST block
//    (threadfence + ticket atomicAdd; deterministic two-half sum order ->
//    bit-identical output regardless of which block runs it; counters zeroed
//    by kSetup each call, reset by the reducer after use).
//  - PX->SX reduce done redundantly by every kConv1 block (4KB, L2-hot).
//  - kFinal folded into kFC2Arc's last block.
// 16 -> 8 dispatches. All verified compute paths unchanged from R16.
// ---------------------------------------------------------------------------

typedef __attribute__((ext_vector_type(8))) short s16x8;
typedef __attribute__((ext_vector_type(8))) _Float16 f16x8;
typedef __attribute__((ext_vector_type(2))) _Float16 h16x2;
typedef __attribute__((ext_vector_type(16))) float f32x16;

__device__ __forceinline__ unsigned short f2bf(float f) {
  __hip_bfloat16 h = __float2bfloat16(f);
  unsigned short u;
  __builtin_memcpy(&u, &h, 2);
  return u;
}
__device__ __forceinline__ float bf2f(unsigned short h) {
  union { unsigned int u; float f; } t; t.u = ((unsigned int)h) << 16; return t.f;
}
__device__ __forceinline__ unsigned short f2h(float f) {
  _Float16 h = (_Float16)f;
  unsigned short u;
  __builtin_memcpy(&u, &h, 2);
  return u;
}

// --- last-block ticket + deterministic tail reduce ---------------------------
__device__ __forceinline__ bool dTicket(int* cnt, int nblocks, int* flg) {
  __threadfence();
  __syncthreads();
  if (threadIdx.x == 0) *flg = (atomicAdd(cnt, 1) == nblocks - 1);
  __syncthreads();
  if (*flg) { __threadfence(); return true; }
  return false;
}
// out[slot] = sum_i part[i*C2+slot]; fixed order: lower half then upper half.
__device__ __forceinline__ void dTailReduce(const float* __restrict__ part,
                                            float* __restrict__ outp,
                                            int nb, int C2, float* lds) {
  int tid = threadIdx.x, nt = blockDim.x;
  int half = nb >> 1;
  for (int e = tid; e < 2 * C2; e += nt) {
    int hh = e >= C2 ? 1 : 0;
    int slot = e - hh * C2;
    int i0 = hh * half, i1 = hh ? nb : half;
    float s = 0.f;
    for (int i = i0; i < i1; i++) s += part[(size_t)i * C2 + slot];
    lds[e] = s;
  }
  __syncthreads();
  for (int slot = tid; slot < C2; slot += nt)
    outp[slot] = lds[slot] + lds[C2 + slot];
}

// ---------------------------------------------------------------------------
// Setup device bodies
// ---------------------------------------------------------------------------
__device__ void dRedX(const float* __restrict__ x, float* __restrict__ part, int b) {
  int tid = threadIdx.x;
  const float4* x4 = (const float4*)x;
  float s = 0.f, q = 0.f;
  for (size_t i = (size_t)b * 256 + tid; i < 802816; i += (size_t)512 * 256) {
    float4 v = x4[i];
    s += v.x + v.y + v.z + v.w;
    q += v.x * v.x + v.y * v.y + v.z * v.z + v.w * v.w;
  }
#pragma unroll
  for (int off = 32; off; off >>= 1) {
    s += __shfl_down(s, off);
    q += __shfl_down(q, off);
  }
  __shared__ float ls[4][2];
  int w = tid >> 6;
  if ((tid & 63) == 0) { ls[w][0] = s; ls[w][1] = q; }
  __syncthreads();
  if (tid == 0) {
    part[b * 2]     = ls[0][0] + ls[1][0] + ls[2][0] + ls[3][0];
    part[b * 2 + 1] = ls[0][1] + ls[1][1] + ls[2][1] + ls[3][1];
  }
}

__device__ void dPrepW(const float* __restrict__ cw1, unsigned short* __restrict__ wf) {
  int tid = threadIdx.x;
  int lane = tid & 63, fb = tid >> 6;
  int m = lane & 31, kg = lane >> 5;
  for (int pass = 0; pass < 9; pass++) {
    int f = pass * 4 + fb;
    int tap = f >> 2, rem = f & 3, kt = rem >> 1, nt = rem & 1;
    int o = nt * 32 + m;
    int kb = kt * 16 + kg * 8;
    union { s16x8 v; unsigned short e[8]; } u;
#pragma unroll
    for (int j = 0; j < 8; j++)
      u.e[j] = f2h(cw1[(size_t)o * 288 + (size_t)(kb + j) * 9 + tap]);
    ((s16x8*)wf)[f * 64 + lane] = u.v;
  }
}

__device__ void dPrepW3(const float* __restrict__ cw, unsigned short* __restrict__ wf3) {
  int tid = threadIdx.x;
  int lane = tid & 63, fq = tid >> 6;
  int m = lane & 31, kg = lane >> 5;
  for (int pass = 0; pass < 9; pass++) {
    int f = pass * 4 + fq;
    int s = f >> 1, nt = f & 1;
    int tap = s >> 1;
    int o = nt * 32 + m;
    int c0 = (s & 1) * 16 + kg * 8;
    union { s16x8 v; unsigned short e[8]; } u;
#pragma unroll
    for (int j = 0; j < 8; j++)
      u.e[j] = f2h(cw[(size_t)o * 288 + (size_t)(c0 + j) * 9 + tap]);
    ((s16x8*)wf3)[f * 64 + lane] = u.v;
  }
}

__device__ void dPrepW1x1(const float* __restrict__ wgt, unsigned short* __restrict__ wfb) {
  int tid = threadIdx.x;
  int l = tid & 63, ks = tid >> 6;
  int o = l & 31, kg = l >> 5;
  union { s16x8 v; unsigned short e[8]; } u;
#pragma unroll
  for (int j = 0; j < 8; j++) {
    int c = ks * 16 + kg * 8 + j;
    u.e[j] = f2h(wgt[o * 64 + c]);
  }
  ((s16x8*)wfb)[ks * 64 + l] = u.v;
}

__device__ void dPrepLW(const float* __restrict__ lw1, unsigned short* __restrict__ wfl, int blk) {
  int tid = threadIdx.x;
  int lane = tid & 63, fq = tid >> 6;
  int m = lane & 31, kg = lane >> 5;
  for (int pp = 0; pp < 4; pp++) {
    int f_idx = (blk * 4 + pp) * 4 + fq;
    int ks = f_idx >> 2, nt = f_idx & 3;
    int f = nt * 32 + m;
    int kb = ks * 16 + kg * 8;
    const float4* src = (const float4*)(lw1 + (size_t)f * 1024 + kb);
    float4 v0 = src[0], v1 = src[1];
    float t[8] = {v0.x, v0.y, v0.z, v0.w, v1.x, v1.y, v1.z, v1.w};
    union { s16x8 v; unsigned short e[8]; } u;
#pragma unroll
    for (int j = 0; j < 8; j++) u.e[j] = f2bf(t[j]);
    ((s16x8*)wfl)[f_idx * 64 + lane] = u.v;
  }
}

__global__ __launch_bounds__(256) void kSetup(
    const float* __restrict__ x, float* __restrict__ PX,
    const float* __restrict__ cw1, unsigned short* __restrict__ WF,
    const float* __restrict__ cw3, unsigned short* __restrict__ WF3,
    const float* __restrict__ cw5, unsigned short* __restrict__ WF5,
    const float* __restrict__ cw2, unsigned short* __restrict__ WC2,
    const float* __restrict__ cw4, unsigned short* __restrict__ WC4,
    const float* __restrict__ lw1, unsigned short* __restrict__ WFL,
    int* __restrict__ CNT) {
  int b = blockIdx.x;
  if (b < 512)       dRedX(x, PX, b);
  else if (b == 512) dPrepW(cw1, WF);
  else if (b == 513) dPrepW3(cw3, WF3);
  else if (b == 514) dPrepW3(cw5, WF5);
  else if (b == 515) dPrepW1x1(cw2, WC2);
  else if (b == 516) dPrepW1x1(cw4, WC4);
  else if (b < 533)  dPrepLW(lw1, WFL, b - 517);
  else               { if (threadIdx.x < 8) CNT[threadIdx.x] = 0; }
}

// ---------------------------------------------------------------------------
// kConv1 (MFMA fp16, split): PX reduced per-block; last block reduces P1->S1.
// ---------------------------------------------------------------------------
__global__ __launch_bounds__(256, 2) void kConv1(
    const float* __restrict__ x, const float* __restrict__ cw0,
    const float* __restrict__ bg0, const float* __restrict__ bb0,
    const float* __restrict__ pa0, const unsigned short* __restrict__ wf,
    const float* __restrict__ PX, unsigned short* __restrict__ y1b,
    float* __restrict__ part, int* __restrict__ cnt, float* __restrict__ S1out) {
  __shared__ __align__(16) unsigned short h0t[13440];
  __shared__ __align__(16) float xbuf[420];   // x stage; reused: sS/sQ; tail scratch
  __shared__ float s0[32], t0[32];
  __shared__ float sxr[8];
  __shared__ int flg;
  int tid = threadIdx.x;
  int n = blockIdx.x >> 1, half = blockIdx.x & 1;
  int l = tid & 63, w = tid >> 6;
  int nt = w & 1, mpair = w >> 1;
  int m = l & 31, kg = l >> 5;
  int npos = half ? 78 : 91;
  int xoff = half ? 392 : 0;
  int nxpix = half ? 364 : 420;

  f16x8 bfr[9][2];
  const f16x8* wfp = (const f16x8*)wf;
#pragma unroll
  for (int tap = 0; tap < 9; tap++)
#pragma unroll
    for (int kt = 0; kt < 2; kt++)
      bfr[tap][kt] = wfp[(tap * 4 + kt * 2 + nt) * 64 + l];

  {
    int nx4 = half ? 91 : 105;
    if (tid < nx4)
      ((float4*)xbuf)[tid] = ((const float4*)(x + (size_t)n * 784 + xoff))[tid];
  }
  // PX reduce (512 pairs): each thread covers i=tid and i=tid+256
  {
    float rs = PX[tid * 2]     + PX[(tid + 256) * 2];
    float rq = PX[tid * 2 + 1] + PX[(tid + 256) * 2 + 1];
#pragma unroll
    for (int off = 32; off; off >>= 1) {
      rs += __shfl_down(rs, off);
      rq += __shfl_down(rq, off);
    }
    if ((tid & 63) == 0) { sxr[(tid >> 6) * 2] = rs; sxr[(tid >> 6) * 2 + 1] = rq; }
  }
  __syncthreads();
  if (tid < 32) {
    float sxs = sxr[0] + sxr[2] + sxr[4] + sxr[6];
    float sxq = sxr[1] + sxr[3] + sxr[5] + sxr[7];
    const float invM = 1.0f / (4096.0f * 784.0f);
    float mux = sxs * invM;
    float varx = fmaxf(sxq * invM - mux * mux, 0.0f);
    float w0 = cw0[tid];
    float inv = rsqrtf(w0 * w0 * varx + 1e-5f);
    float sc = w0 * bg0[tid] * inv;
    s0[tid] = sc;
    t0[tid] = bb0[tid] - mux * sc;
  }
  __syncthreads();

  float a0p = *pa0;
  _Float16 a1h = (_Float16)a0p;
  h16x2 a2 = {a1h, a1h};
  h16x2 z2 = {(_Float16)0.0f, (_Float16)0.0f};
  int g = tid & 3;
  h16x2 sg2[4], tg2[4];
#pragma unroll
  for (int j = 0; j < 4; j++) {
    sg2[j] = (h16x2){(_Float16)s0[g * 8 + 2 * j], (_Float16)s0[g * 8 + 2 * j + 1]};
    tg2[j] = (h16x2){(_Float16)t0[g * 8 + 2 * j], (_Float16)t0[g * 8 + 2 * j + 1]};
  }
  char* h0b = (char*)h0t;
  int koffW = g * 16;
  for (int t = 0; t < 7; t++) {
    int p = (tid >> 2) + t * 64;
    if (p < nxpix) {
      _Float16 xh = (_Float16)xbuf[p];
      h16x2 x2 = {xh, xh};
      union { f16x8 v; h16x2 h2[4]; } u;
#pragma unroll
      for (int j = 0; j < 4; j++) {
        h16x2 tv = x2 * sg2[j] + tg2[j];
        u.h2[j] = a2 * __builtin_elementwise_min(tv, z2) +
                  __builtin_elementwise_max(tv, z2);
      }
      int ad = ((p << 6) + koffW) ^ (((p >> 1) & 7) << 4);
      *(f16x8*)(h0b + ad) = u.v;
    }
  }
  __syncthreads();

  int tA = mpair ? 2 : 0;
  int lpA = tA * 32 + m; lpA = lpA > npos - 1 ? npos - 1 : lpA;
  int lpB = 32 + m;      lpB = lpB > npos - 1 ? npos - 1 : lpB;
  int pixbA = (lpA / 13) * 56 + (lpA % 13) * 2;
  int pixbB = (lpB / 13) * 56 + (lpB % 13) * 2;
  int koffA = kg * 16;

#define Z16 {0.f,0.f,0.f,0.f, 0.f,0.f,0.f,0.f, 0.f,0.f,0.f,0.f, 0.f,0.f,0.f,0.f}
  f32x16 acc0 = Z16, acc1 = Z16;

#define MT_STEP(ACC, PB) { \
  _Pragma("unroll") for (int tap = 0; tap < 9; tap++) { \
    int pix = (PB) + (tap / 3) * 28 + (tap % 3); \
    int ad = ((pix << 6) + koffA) ^ (((pix >> 1) & 7) << 4); \
    f16x8 a0 = *(const f16x8*)(h0b + ad); \
    f16x8 a1 = *(const f16x8*)(h0b + (ad ^ 32)); \
    ACC = __builtin_amdgcn_mfma_f32_32x32x16_f16(a0, bfr[tap][0], ACC, 0, 0, 0); \
    ACC = __builtin_amdgcn_mfma_f32_32x32x16_f16(a1, bfr[tap][1], ACC, 0, 0, 0); \
  } }

  MT_STEP(acc0, pixbA)
  if (mpair == 0) { MT_STEP(acc1, pixbB) }
#undef MT_STEP

  __syncthreads();
  unsigned short* ystage = h0t;
  float* sSf = xbuf;
  float* sQf = xbuf + 128;
  float s = 0.f, q = 0.f;
  int och = nt * 32 + m;
#define ST_MT(ACC, TILE) { int pbase = (TILE) * 32 + (kg << 2); \
  _Pragma("unroll") for (int r = 0; r < 16; r++) { \
    int p = pbase + (r & 3) + ((r >> 2) << 3); \
    if (p < npos) { float v = ACC[r]; \
      ystage[p * 64 + och] = f2h(v); s += v; q += v * v; } } }

  ST_MT(acc0, tA)
  if (mpair == 0) { ST_MT(acc1, 1) }
#undef ST_MT

  s += __shfl_xor(s, 32);
  q += __shfl_xor(q, 32);
  if (l < 32) { sSf[w * 32 + l] = s; sQf[w * 32 + l] = q; }
  __syncthreads();
  {
    int nseg = npos * 8;
    const s16x8* src8 = (const s16x8*)ystage;
    s16x8* dst8 = (s16x8*)(y1b + (size_t)n * 10816 + half * 5824);
    for (int e = tid; e < nseg; e += 256) dst8[e] = src8[e];
  }
  if (tid < 64) {
    int o = tid, wv = o >> 5;
    part[(size_t)blockIdx.x * 128 + o] =
        sSf[wv * 32 + (o & 31)] + sSf[(wv + 2) * 32 + (o & 31)];
  } else if (tid < 128) {
    int o = tid - 64, wv = o >> 5;
    part[(size_t)blockIdx.x * 128 + 64 + o] =
        sQf[wv * 32 + (o & 31)] + sQf[(wv + 2) * 32 + (o & 31)];
  }
  // tail: last block reduces P1 -> S1 (xbuf as scratch, 256 floats needed)
  if (dTicket(cnt, 8192, &flg)) {
    dTailReduce(part, S1out, 8192, 128, xbuf);
    if (tid == 0) *cnt = 0;
  }
}

// ---------------------------------------------------------------------------
// kConv1x1m (fp16): last block reduces its partials (C2=64).
// ---------------------------------------------------------------------------
__global__ __launch_bounds__(256, 4) void kConv1x1m(
    const unsigned short* __restrict__ wfb, const float* __restrict__ g,
    const float* __restrict__ b, const float* __restrict__ pa,
    const float* __restrict__ stats, float invM,
    const unsigned short* __restrict__ in, unsigned short* __restrict__ outb,
    float* __restrict__ part, int* __restrict__ cnt, float* __restrict__ Sout,
    int nblocks) {
  __shared__ __align__(16) unsigned short hs[128 * 64];
  __shared__ float scs[64], shs[64];
  __shared__ float sS[4][32], sQ[4][32];
  __shared__ float redbuf[128];
  __shared__ int flg;
  int tid = threadIdx.x;
  size_t r0 = (size_t)blockIdx.x * 128;
  int l = tid & 63, w = tid >> 6;
  int m = l & 31, kg = l >> 5;

  f16x8 bfr[4];
  const f16x8* bp = (const f16x8*)wfb;
#pragma unroll
  for (int ks = 0; ks < 4; ks++) bfr[ks] = bp[ks * 64 + l];

  if (tid < 64) {
    float mu = stats[tid] * invM;
    float va = fmaxf(stats[64 + tid] * invM - mu * mu, 0.0f);
    float iv = rsqrtf(va + 1e-5f);
    float sc = g[tid] * iv;
    scs[tid] = sc;
    shs[tid] = b[tid] - mu * sc;
  }
  __syncthreads();
  float al = *pa;
  _Float16 alh = (_Float16)al;
  h16x2 a2 = {alh, alh};
  h16x2 z2 = {(_Float16)0.0f, (_Float16)0.0f};
  int seg0 = tid & 7;
  h16x2 sc2[4], sh2[4];
#pragma unroll
  for (int j = 0; j < 4; j++) {
    int c = seg0 * 8 + 2 * j;
    sc2[j] = (h16x2){(_Float16)scs[c], (_Float16)scs[c + 1]};
    sh2[j] = (h16x2){(_Float16)shs[c], (_Float16)shs[c + 1]};
  }
  char* hb = (char*)hs;
#pragma unroll
  for (int i = 0; i < 4; i++) {
    int e = tid + i * 256;
    int row = e >> 3;
    union { f16x8 v; h16x2 h2[4]; } u, o8;
    u.v = *(const f16x8*)(in + (r0 + row) * 64 + seg0 * 8);
#pragma unroll
    for (int j = 0; j < 4; j++) {
      h16x2 tv = u.h2[j] * sc2[j] + sh2[j];
      o8.h2[j] = a2 * __builtin_elementwise_min(tv, z2) +
                 __builtin_elementwise_max(tv, z2);
    }
    int ad = (row * 128 + seg0 * 16) ^ ((row & 7) << 4);
    *(f16x8*)(hb + ad) = o8.v;
  }
  __syncthreads();

#define Z16 {0.f,0.f,0.f,0.f, 0.f,0.f,0.f,0.f, 0.f,0.f,0.f,0.f, 0.f,0.f,0.f,0.f}
  f32x16 acc = Z16;
#undef Z16
  int rloc = w * 32 + m;
  int abase = (rloc * 128 + kg * 16) ^ ((rloc & 7) << 4);
#pragma unroll
  for (int ks = 0; ks < 4; ks++) {
    f16x8 a = *(const f16x8*)(hb + (abase ^ (ks * 32)));
    acc = __builtin_amdgcn_mfma_f32_32x32x16_f16(a, bfr[ks], acc, 0, 0, 0);
  }

  float ss = 0.f, qq = 0.f;
#pragma unroll
  for (int rr = 0; rr < 16; rr++) {
    int rowt = (rr & 3) + ((rr >> 2) << 3) + (kg << 2);
    float v = acc[rr];
    outb[(r0 + (size_t)w * 32 + rowt) * 32 + m] = f2h(v);
    ss += v; qq += v * v;
  }
  ss += __shfl_xor(ss, 32);
  qq += __shfl_xor(qq, 32);
  if (l < 32) { sS[w][l] = ss; sQ[w][l] = qq; }
  __syncthreads();
  if (tid < 32) {
    part[(size_t)blockIdx.x * 64 + tid] = sS[0][tid] + sS[1][tid] + sS[2][tid] + sS[3][tid];
  } else if (tid < 64) {
    int o = tid - 32;
    part[(size_t)blockIdx.x * 64 + 32 + o] = sQ[0][o] + sQ[1][o] + sQ[2][o] + sQ[3][o];
  }
  if (dTicket(cnt, nblocks, &flg)) {
    dTailReduce(part, Sout, nblocks, 64, redbuf);
    if (tid == 0) *cnt = 0;
  }
}

// ---------------------------------------------------------------------------
// kConv3m (fp16): last block reduces P3 -> S3 (C2=128).
// ---------------------------------------------------------------------------
__global__ __launch_bounds__(256, 3) void kConv3m(
    const unsigned short* __restrict__ wf3, const float* __restrict__ g,
    const float* __restrict__ b, const float* __restrict__ pa,
    const float* __restrict__ stats, const unsigned short* __restrict__ in,
    unsigned short* __restrict__ outb, float* __restrict__ part,
    int* __restrict__ cnt, float* __restrict__ Sout) {
  __shared__ __align__(16) unsigned short h2t[169 * 32];
  __shared__ float scs[32], shs[32];
  __shared__ float sS[4][32], sQ[4][32];
  __shared__ float redbuf[256];
  __shared__ int flg;
  int tid = threadIdx.x;
  int n = blockIdx.x;
  int l = tid & 63, w = tid >> 6;
  int nt = w & 1, mt = w >> 1;
  int m = l & 31, kg = l >> 5;

  f16x8 bfr[18];
  const f16x8* wfp = (const f16x8*)wf3;
#pragma unroll
  for (int s = 0; s < 18; s++) bfr[s] = wfp[(s * 2 + nt) * 64 + l];

  if (tid < 32) {
    const float invM = 1.0f / 692224.0f;
    float mu = stats[tid] * invM;
    float va = fmaxf(stats[32 + tid] * invM - mu * mu, 0.0f);
    float iv = rsqrtf(va + 1e-5f);
    float sc = g[tid] * iv;
    scs[tid] = sc;
    shs[tid] = b[tid] - mu * sc;
  }
  __syncthreads();
  float al = *pa;
  _Float16 alh = (_Float16)al;
  h16x2 a2 = {alh, alh};
  h16x2 z2 = {(_Float16)0.0f, (_Float16)0.0f};
  int q0 = tid & 3;
  h16x2 sc2[4], sh2[4];
#pragma unroll
  for (int j = 0; j < 4; j++) {
    int c = q0 * 8 + 2 * j;
    sc2[j] = (h16x2){(_Float16)scs[c], (_Float16)scs[c + 1]};
    sh2[j] = (h16x2){(_Float16)shs[c], (_Float16)shs[c + 1]};
  }
  char* hb = (char*)h2t;
  for (int e = tid; e < 676; e += 256) {
    int p = e >> 2;
    union { f16x8 v; h16x2 h2[4]; } u, o8;
    u.v = ((const f16x8*)(in + ((size_t)n * 169 + p) * 32))[q0];
#pragma unroll
    for (int j = 0; j < 4; j++) {
      h16x2 tv = u.h2[j] * sc2[j] + sh2[j];
      o8.h2[j] = a2 * __builtin_elementwise_min(tv, z2) +
                 __builtin_elementwise_max(tv, z2);
    }
    int ad = ((p << 6) + q0 * 16) ^ (((p >> 1) & 7) << 4);
    *(f16x8*)(hb + ad) = o8.v;
  }
  __syncthreads();

  int p = mt * 32 + m;
  p = p > 35 ? 35 : p;
  int pixb = (p / 6) * 26 + (p % 6) * 2;

#define Z16 {0.f,0.f,0.f,0.f, 0.f,0.f,0.f,0.f, 0.f,0.f,0.f,0.f, 0.f,0.f,0.f,0.f}
  f32x16 acc = Z16;
#undef Z16
#pragma unroll
  for (int s = 0; s < 18; s++) {
    int tap = s >> 1;
    int pix = pixb + (tap / 3) * 13 + (tap % 3);
    int ad = ((pix << 6) + (s & 1) * 32 + kg * 16) ^ (((pix >> 1) & 7) << 4);
    f16x8 a = *(const f16x8*)(hb + ad);
    acc = __builtin_amdgcn_mfma_f32_32x32x16_f16(a, bfr[s], acc, 0, 0, 0);
  }

  float ss = 0.f, qq = 0.f;
  int och = nt * 32 + m;
#pragma unroll
  for (int r = 0; r < 16; r++) {
    int row = (r & 3) + ((r >> 2) << 3) + (kg << 2);
    int pp = mt * 32 + row;
    if (pp < 36) {
      float v = acc[r];
      outb[((size_t)n * 36 + pp) * 64 + och] = f2h(v);
      ss += v; qq += v * v;
    }
  }
  ss += __shfl_xor(ss, 32);
  qq += __shfl_xor(qq, 32);
  if (l < 32) { sS[w][l] = ss; sQ[w][l] = qq; }
  __syncthreads();
  if (tid < 64) {
    int o = tid, wv = o >> 5;
    part[(size_t)n * 128 + o] = sS[wv][o & 31] + sS[wv + 2][o & 31];
  } else if (tid < 128) {
    int o = tid - 64, wv = o >> 5;
    part[(size_t)n * 128 + 64 + o] = sQ[wv][o & 31] + sQ[wv + 2][o & 31];
  }
  if (dTicket(cnt, 4096, &flg)) {
    dTailReduce(part, Sout, 4096, 128, redbuf);
    if (tid == 0) *cnt = 0;
  }
}

// ---------------------------------------------------------------------------
// kConv5m (fp16): last block reduces P5 -> S5 (C2=128; blockDim=128).
// ---------------------------------------------------------------------------
__global__ __launch_bounds__(128) void kConv5m(
    const unsigned short* __restrict__ wf5, const float* __restrict__ g,
    const float* __restrict__ b, const float* __restrict__ pa,
    const float* __restrict__ stats, const unsigned short* __restrict__ in,
    float* __restrict__ outb, float* __restrict__ part,
    int* __restrict__ cnt, float* __restrict__ Sout) {
  __shared__ __align__(16) unsigned short h4t[2 * 1280];
  __shared__ float scs[32], shs[32];
  __shared__ float redbuf[256];
  __shared__ int flg;
  int tid = threadIdx.x;
  int nA = blockIdx.x * 2;
  int l = tid & 63, w = tid >> 6;
  int m = l & 31, kg = l >> 5;

  f16x8 bfr[18];
  const f16x8* wfp = (const f16x8*)wf5;
#pragma unroll
  for (int s = 0; s < 18; s++) bfr[s] = wfp[(s * 2 + w) * 64 + l];

  if (tid < 32) {
    const float invM = 1.0f / 147456.0f;
    float mu = stats[tid] * invM;
    float va = fmaxf(stats[32 + tid] * invM - mu * mu, 0.0f);
    float iv = rsqrtf(va + 1e-5f);
    float sc = g[tid] * iv;
    scs[tid] = sc;
    shs[tid] = b[tid] - mu * sc;
  }
  __syncthreads();
  float al = *pa;
  _Float16 alh = (_Float16)al;
  h16x2 a2 = {alh, alh};
  h16x2 z2 = {(_Float16)0.0f, (_Float16)0.0f};
  int q0 = tid & 3;
  h16x2 sc2[4], sh2[4];
#pragma unroll
  for (int j = 0; j < 4; j++) {
    int c = q0 * 8 + 2 * j;
    sc2[j] = (h16x2){(_Float16)scs[c], (_Float16)scs[c + 1]};
    sh2[j] = (h16x2){(_Float16)shs[c], (_Float16)shs[c + 1]};
  }
  char* hb = (char*)h4t;
  for (int e = tid; e < 288; e += 128) {
    int img = e >= 144;
    int rem = e - img * 144;
    int p = rem >> 2;
    union { f16x8 v; h16x2 h2[4]; } u, o8;
    u.v = ((const f16x8*)(in + ((size_t)(nA + img) * 36 + p) * 32))[q0];
#pragma unroll
    for (int j = 0; j < 4; j++) {
      h16x2 tv = u.h2[j] * sc2[j] + sh2[j];
      o8.h2[j] = a2 * __builtin_elementwise_min(tv, z2) +
                 __builtin_elementwise_max(tv, z2);
    }
    int ad = img * 2560 + (((p << 6) + q0 * 16) ^ (((p >> 1) & 7) << 4));
    *(f16x8*)(hb + ad) = o8.v;
  }
  __syncthreads();

  int imgl = m >> 4;
  int pl = m & 15;
  int pixb = (pl >> 2) * 6 + (pl & 3);
  int ibase = imgl * 2560;

#define Z16 {0.f,0.f,0.f,0.f, 0.f,0.f,0.f,0.f, 0.f,0.f,0.f,0.f, 0.f,0.f,0.f,0.f}
  f32x16 acc = Z16;
#undef Z16
#pragma unroll
  for (int s = 0; s < 18; s++) {
    int tap = s >> 1;
    int pix = pixb + (tap / 3) * 6 + (tap % 3);
    int ad = ibase + (((pix << 6) + (s & 1) * 32 + kg * 16) ^ (((pix >> 1) & 7) << 4));
    f16x8 a = *(const f16x8*)(hb + ad);
    acc = __builtin_amdgcn_mfma_f32_32x32x16_f16(a, bfr[s], acc, 0, 0, 0);
  }

  float ss = 0.f, qq = 0.f;
  int och = w * 32 + m;
#pragma unroll
  for (int r = 0; r < 16; r++) {
    int row = (r & 3) + ((r >> 2) << 3) + (kg << 2);
    int img = row >> 4, p = row & 15;
    float v = acc[r];
    outb[(size_t)(nA + img) * 1024 + och * 16 + p] = v;
    ss += v; qq += v * v;
  }
  ss += __shfl_xor(ss, 32);
  qq += __shfl_xor(qq, 32);
  if (l < 32) {
    part[(size_t)blockIdx.x * 128 + w * 32 + l] = ss;
    part[(size_t)blockIdx.x * 128 + 64 + w * 32 + l] = qq;
  }
  if (dTicket(cnt, 2048, &flg)) {
    dTailReduce(part, Sout, 2048, 128, redbuf);
    if (tid == 0) *cnt = 0;
  }
}

// ---------------------------------------------------------------------------
// kFC1m: last block reduces P6 -> S6 (C2=256; blockDim=128).
// ---------------------------------------------------------------------------
__global__ __launch_bounds__(128) void kFC1m(
    const unsigned short* __restrict__ wfl, const float* __restrict__ g,
    const float* __restrict__ b, const float* __restrict__ pa,
    const float* __restrict__ stats, const float* __restrict__ y5,
    float* __restrict__ z, float* __restrict__ part,
    int* __restrict__ cnt, float* __restrict__ Sout) {
  __shared__ __align__(16) unsigned short hs[32 * 1024];
  __shared__ float scs[64], shs[64];
  __shared__ float redbuf[512];
  __shared__ int flg;
  int tid = threadIdx.x;
  int n0 = blockIdx.x * 32;
  if (tid < 64) {
    const float invM = 1.0f / 65536.0f;
    float mu = stats[tid] * invM;
    float va = fmaxf(stats[64 + tid] * invM - mu * mu, 0.0f);
    float iv = rsqrtf(va + 1e-5f);
    float sc = g[tid] * iv;
    scs[tid] = sc;
    shs[tid] = b[tid] - mu * sc;
  }
  __syncthreads();
  float al = *pa;
  char* hb = (char*)hs;
  for (int i = 0; i < 32; i++) {
    int sgi = tid + i * 128;
    int nn = sgi >> 7, k8 = sgi & 127;
    int c = k8 >> 1;
    float sc = scs[c], sh = shs[c];
    const float4* src = (const float4*)(y5 + (size_t)(n0 + nn) * 1024 + k8 * 8);
    float4 v0 = src[0], v1 = src[1];
    float t[8] = {v0.x, v0.y, v0.z, v0.w, v1.x, v1.y, v1.z, v1.w};
    union { s16x8 v; unsigned short e[8]; } u;
#pragma unroll
    for (int j = 0; j < 8; j++) {
      float h = fmaf(t[j], sc, sh);
      h = h > 0.f ? h : al * h;
      u.e[j] = f2bf(h);
    }
    int ad = (nn * 2048 + k8 * 16) ^ ((nn & 7) << 4);
    *(s16x8*)(hb + ad) = u.v;
  }
  __syncthreads();

  int l = tid & 63, w = tid >> 6;
  int m = l & 31, kg = l >> 5;
#define Z16 {0.f,0.f,0.f,0.f, 0.f,0.f,0.f,0.f, 0.f,0.f,0.f,0.f, 0.f,0.f,0.f,0.f}
  f32x16 acc0 = Z16, acc1 = Z16;
#undef Z16
  const s16x8* bp = (const s16x8*)wfl;
  int abase = (m * 2048 + kg * 16) ^ ((m & 7) << 4);
#pragma unroll 4
  for (int ks = 0; ks < 64; ks++) {
    s16x8 a = *(const s16x8*)(hb + (abase ^ (ks * 32)));
    s16x8 b0 = bp[(ks * 4 + 2 * w + 0) * 64 + l];
    s16x8 b1 = bp[(ks * 4 + 2 * w + 1) * 64 + l];
    acc0 = __builtin_amdgcn_mfma_f32_32x32x16_bf16(a, b0, acc0, 0, 0, 0);
    acc1 = __builtin_amdgcn_mfma_f32_32x32x16_bf16(a, b1, acc1, 0, 0, 0);
  }

  float s0 = 0.f, q0 = 0.f, s1 = 0.f, q1 = 0.f;
  int f0c = (2 * w) * 32 + m, f1c = (2 * w + 1) * 32 + m;
#pragma unroll
  for (int r = 0; r < 16; r++) {
    int n = (r & 3) + ((r >> 2) << 3) + (kg << 2);
    float v0 = acc0[r], v1 = acc1[r];
    z[(size_t)(n0 + n) * 128 + f0c] = v0;
    z[(size_t)(n0 + n) * 128 + f1c] = v1;
    s0 += v0; q0 += v0 * v0; s1 += v1; q1 += v1 * v1;
  }
  s0 += __shfl_xor(s0, 32); q0 += __shfl_xor(q0, 32);
  s1 += __shfl_xor(s1, 32); q1 += __shfl_xor(q1, 32);
  if (l < 32) {
    size_t base = (size_t)blockIdx.x * 256;
    part[base + w * 64 + m] = s0;
    part[base + w * 64 + 32 + m] = s1;
    part[base + 128 + w * 64 + m] = q0;
    part[base + 128 + w * 64 + 32 + m] = q1;
  }
  if (dTicket(cnt, 128, &flg)) {
    dTailReduce(part, Sout, 128, 256, redbuf);
    if (tid == 0) *cnt = 0;
  }
}

// ---------------------------------------------------------------------------
// kFC2Arc: last block sums lpart -> final loss (replaces kFinal).
// ---------------------------------------------------------------------------
__global__ __launch_bounds__(256) void kFC2Arc(
    const float* __restrict__ z, const float* __restrict__ s6,
    const float* __restrict__ lg1, const float* __restrict__ lb1,
    const float* __restrict__ pl1, const float* __restrict__ lw2,
    const float* __restrict__ lb2, const float* __restrict__ aw,
    const int* __restrict__ labels, float* __restrict__ out,
    float* __restrict__ lpart, int* __restrict__ cnt) {
  __shared__ float scz[128], shz[128], w2a[128], w2b[128];
  __shared__ float awl[20];
  __shared__ float lred[4];
  __shared__ int flg;
  int tid = threadIdx.x;
  if (tid < 128) {
    const float invM = 1.0f / 4096.0f;
    float mu = s6[tid] * invM;
    float va = fmaxf(s6[128 + tid] * invM - mu * mu, 0.0f);
    float iv = rsqrtf(va + 1e-5f);
    float sc = lg1[tid] * iv;
    scz[tid] = sc;
    shz[tid] = lb1[tid] - mu * sc;
    w2a[tid] = lw2[tid];
    w2b[tid] = lw2[128 + tid];
  }
  if (tid < 20) awl[tid] = aw[tid];
  __syncthreads();
  float al = *pl1;
  int n = blockIdx.x * 256 + tid;
  const float4* zr = (const float4*)(z + (size_t)n * 128);
  float f0 = lb2[0], f1 = lb2[1];
#pragma unroll
  for (int kb = 0; kb < 32; kb++) {
    float4 v = zr[kb];
    float hv[4] = {v.x, v.y, v.z, v.w};
#pragma unroll
    for (int u = 0; u < 4; u++) {
      int k = kb * 4 + u;
      float h = fmaf(hv[u], scz[k], shz[k]);
      h = h > 0.f ? h : al * h;
      f0 = fmaf(h, w2a[k], f0);
      f1 = fmaf(h, w2b[k], f1);
    }
  }
  out[(size_t)n * 2] = f0;
  out[(size_t)n * 2 + 1] = f1;
  float nrm = sqrtf(fmaxf(f0 * f0 + f1 * f1, 1e-30f));
  float xn0 = f0 / nrm, xn1 = f1 / nrm;
  int lab = labels[n];
  float wv[10];
  float m64 = -3.4e38f;
#pragma unroll
  for (int j = 0; j < 10; j++) {
    float w = xn0 * awl[2 * j] + xn1 * awl[2 * j + 1];
    wv[j] = w;
    out[8192 + (size_t)n * 10 + j] = w;
    m64 = fmaxf(m64, 64.0f * w);
  }
  float tgt = wv[0];
#pragma unroll
  for (int j = 1; j < 10; j++) if (j == lab) tgt = wv[j];
  if (lab == 0) tgt = wv[0];
  const float CLO = (float)(-1.0 + 1e-7);
  const float CHI = (float)(1.0 - 1e-7);
  float t = fminf(fmaxf(tgt, CLO), CHI);
  float num = 64.0f * (t * 0.87758256189037276f - 0.47942553860420301f * sqrtf(fmaxf(1.0f - t * t, 0.0f)));
  float L = fmaxf(num, m64);
  float dsum = expf(num - L) - expf(64.0f * tgt - L);
#pragma unroll
  for (int j = 0; j < 10; j++) dsum += expf(64.0f * wv[j] - L);
  dsum = fmaxf(dsum, 1e-30f);
  float li = num - (L + logf(dsum));
#pragma unroll
  for (int off = 32; off; off >>= 1) li += __shfl_down(li, off);
  if ((tid & 63) == 0) lred[tid >> 6] = li;
  __syncthreads();
  if (tid == 0) lpart[blockIdx.x] = lred[0] + lred[1] + lred[2] + lred[3];
  if (dTicket(cnt, 16, &flg)) {
    if (tid == 0) {
      float ssum = 0.f;
      for (int i = 0; i < 16; i++) ssum += lpart[i];
      out[49152] = -ssum * (1.0f / 4096.0f);
      *cnt = 0;
    }
  }
}

// ---------------------------------------------------------------------------
extern "C" void kernel_launch(void* const* d_in, const int* in_sizes, int n_in,
                              void* d_out, int out_size, void* d_ws, size_t ws_size,
                              hipStream_t stream) {
  const float* x   = (const float*)d_in[0];
  const int* labels = (const int*)d_in[1];
  const float* cw0 = (const float*)d_in[2];
  const float* bg0 = (const float*)d_in[3];
  const float* bb0 = (const float*)d_in[4];
  const float* pa0 = (const float*)d_in[5];
  const float* cw1 = (const float*)d_in[6];
  const float* bg1 = (const float*)d_in[7];
  const float* bb1 = (const float*)d_in[8];
  const float* pa1 = (const float*)d_in[9];
  const float* cw2 = (const float*)d_in[10];
  const float* bg2 = (const float*)d_in[11];
  const float* bb2 = (const float*)d_in[12];
  const float* pa2 = (const float*)d_in[13];
  const float* cw3 = (const float*)d_in[14];
  const float* bg3 = (const float*)d_in[15];
  const float* bb3 = (const float*)d_in[16];
  const float* pa3 = (const float*)d_in[17];
  const float* cw4 = (const float*)d_in[18];
  const float* bg4 = (const float*)d_in[19];
  const float* bb4 = (const float*)d_in[20];
  const float* pa4 = (const float*)d_in[21];
  const float* cw5 = (const float*)d_in[22];
  const float* bg5 = (const float*)d_in[23];
  const float* bb5 = (const float*)d_in[24];
  const float* pa5 = (const float*)d_in[25];
  const float* lw1 = (const float*)d_in[26];
  const float* lg1 = (const float*)d_in[27];
  const float* lb1 = (const float*)d_in[28];
  const float* pl1 = (const float*)d_in[29];
  const float* lw2 = (const float*)d_in[30];
  const float* lb2 = (const float*)d_in[31];
  const float* aw  = (const float*)d_in[32];
  float* out = (float*)d_out;
  float* ws = (float*)d_ws;

  float* PX = ws;                    // 1024
  float* S1 = ws + 1040;             // 128
  float* S2 = ws + 1168;             // 64
  float* S3 = ws + 1232;             // 128
  float* S4 = ws + 1360;             // 64
  float* S5 = ws + 1424;             // 128
  float* S6 = ws + 1552;             // 256
  float* LP = ws + 1808;             // 16
  float* P1 = ws + 2048;             // [8192][128]
  float* P2 = P1 + 1048576;          // [5408][64]
  float* P3 = P2 + 346112;           // [4096][128]
  float* P4 = P3 + 524288;           // [1152][64]
  float* P5 = P4 + 73728;            // [2048][128]
  float* P6 = P1;                    // [128][256] — aliases dead P1
  unsigned short* Y1 = (unsigned short*)(ws + (size_t)2359296);  // [4096][169][64] fp16
  unsigned short* Y2 = Y1 + (size_t)44302336;  // [4096][169][32] fp16
  unsigned short* Y3 = Y2 + (size_t)22151168;  // [4096][36][64] fp16
  unsigned short* Y4 = Y3 + (size_t)9437184;   // [4096][36][32] fp16
  float* Y5 = (float*)(Y4 + (size_t)4718592);  // [4096][1024] fp32 k-order
  float* Z  = Y5 + (size_t)4194304;  // [4096][128]
  float* WF = Z + 524288;            // conv1 weight frags (fp16)
  float* WFL = WF + 16384;           // lw1 frags (bf16)
  float* WF3 = WFL + 65536;          // conv3 weight frags (fp16)
  float* WC2 = WF3 + 16384;          // conv2 1x1 frags
  float* WC4 = WC2 + 1024;           // conv4 1x1 frags
  float* WF5 = WC4 + 1024;           // conv5 weight frags
  int* CNT = (int*)(WF5 + 9216);     // 8 counters

  kSetup<<<534, 256, 0, stream>>>(x, PX, cw1, (unsigned short*)WF,
                                  cw3, (unsigned short*)WF3,
                                  cw5, (unsigned short*)WF5,
                                  cw2, (unsigned short*)WC2,
                                  cw4, (unsigned short*)WC4,
                                  lw1, (unsigned short*)WFL, CNT);
  kConv1<<<8192, 256, 0, stream>>>(x, cw0, bg0, bb0, pa0, (const unsigned short*)WF,
                                   PX, Y1, P1, &CNT[0], S1);
  kConv1x1m<<<5408, 256, 0, stream>>>((const unsigned short*)WC2, bg1, bb1, pa1, S1,
                                      1.0f / 692224.0f, Y1, Y2, P2, &CNT[1], S2, 5408);
  kConv3m<<<4096, 256, 0, stream>>>((const unsigned short*)WF3, bg2, bb2, pa2, S2,
                                    Y2, Y3, P3, &CNT[2], S3);
  kConv1x1m<<<1152, 256, 0, stream>>>((const unsigned short*)WC4, bg3, bb3, pa3, S3,
                                      1.0f / 147456.0f, Y3, Y4, P4, &CNT[3], S4, 1152);
  kConv5m<<<2048, 128, 0, stream>>>((const unsigned short*)WF5, bg4, bb4, pa4, S4,
                                    Y4, Y5, P5, &CNT[4], S5);
  kFC1m<<<128, 128, 0, stream>>>((const unsigned short*)WFL, bg5, bb5, pa5, S5,
                                 Y5, Z, P6, &CNT[5], S6);
  kFC2Arc<<<16, 256, 0, stream>>>(Z, S6, lg1, lb1, pl1, lw2, lb2, aw, labels, out,
                                  LP, &CNT[6]);
}

// Round 18
// 209.119 us; speedup vs baseline: 24.7985x; 24.7985x over previous
//
#include <hip/hip_runtime.h>
#include <hip/hip_bf16.h>
#include <hip/hip_fp16.h>
#include <math.h>

// ---------------------------------------------------------------------------
// R18 = exact revert to R16 (209us, passing). R17's last-block ticket fusion
// regressed 25x: device-scope __threadfence + single-address atomicAdd from
// every block serializes across the 8 non-coherent XCD L2s (~200-250ns each x
// 21k blocks ~= 5ms). Lesson: per-block cross-XCD coherence ops are far more
// expensive than the few-us-per-launch dispatch overhead they remove.
// ---------------------------------------------------------------------------

typedef __attribute__((ext_vector_type(8))) short s16x8;
typedef __attribute__((ext_vector_type(8))) _Float16 f16x8;
typedef __attribute__((ext_vector_type(2))) _Float16 h16x2;
typedef __attribute__((ext_vector_type(16))) float f32x16;

__device__ __forceinline__ unsigned short f2bf(float f) {
  __hip_bfloat16 h = __float2bfloat16(f);
  unsigned short u;
  __builtin_memcpy(&u, &h, 2);
  return u;
}
__device__ __forceinline__ float bf2f(unsigned short h) {
  union { unsigned int u; float f; } t; t.u = ((unsigned int)h) << 16; return t.f;
}
__device__ __forceinline__ unsigned short f2h(float f) {
  _Float16 h = (_Float16)f;
  unsigned short u;
  __builtin_memcpy(&u, &h, 2);
  return u;
}

// ---------------------------------------------------------------------------
// Setup device bodies
// ---------------------------------------------------------------------------
__device__ void dRedX(const float* __restrict__ x, float* __restrict__ part, int b) {
  int tid = threadIdx.x;
  const float4* x4 = (const float4*)x;
  float s = 0.f, q = 0.f;
  for (size_t i = (size_t)b * 256 + tid; i < 802816; i += (size_t)512 * 256) {
    float4 v = x4[i];
    s += v.x + v.y + v.z + v.w;
    q += v.x * v.x + v.y * v.y + v.z * v.z + v.w * v.w;
  }
#pragma unroll
  for (int off = 32; off; off >>= 1) {
    s += __shfl_down(s, off);
    q += __shfl_down(q, off);
  }
  __shared__ float ls[4][2];
  int w = tid >> 6;
  if ((tid & 63) == 0) { ls[w][0] = s; ls[w][1] = q; }
  __syncthreads();
  if (tid == 0) {
    part[b * 2]     = ls[0][0] + ls[1][0] + ls[2][0] + ls[3][0];
    part[b * 2 + 1] = ls[0][1] + ls[1][1] + ls[2][1] + ls[3][1];
  }
}

// conv1 weights -> fp16 frags
__device__ void dPrepW(const float* __restrict__ cw1, unsigned short* __restrict__ wf) {
  int tid = threadIdx.x;
  int lane = tid & 63, fb = tid >> 6;
  int m = lane & 31, kg = lane >> 5;
  for (int pass = 0; pass < 9; pass++) {
    int f = pass * 4 + fb;
    int tap = f >> 2, rem = f & 3, kt = rem >> 1, nt = rem & 1;
    int o = nt * 32 + m;
    int kb = kt * 16 + kg * 8;
    union { s16x8 v; unsigned short e[8]; } u;
#pragma unroll
    for (int j = 0; j < 8; j++)
      u.e[j] = f2h(cw1[(size_t)o * 288 + (size_t)(kb + j) * 9 + tap]);
    ((s16x8*)wf)[f * 64 + lane] = u.v;
  }
}

// 3x3 weights [64o][32c][3][3] -> 36 fp16 frags, k-order tap*32+c
__device__ void dPrepW3(const float* __restrict__ cw, unsigned short* __restrict__ wf3) {
  int tid = threadIdx.x;
  int lane = tid & 63, fq = tid >> 6;
  int m = lane & 31, kg = lane >> 5;
  for (int pass = 0; pass < 9; pass++) {
    int f = pass * 4 + fq;
    int s = f >> 1, nt = f & 1;
    int tap = s >> 1;
    int o = nt * 32 + m;
    int c0 = (s & 1) * 16 + kg * 8;
    union { s16x8 v; unsigned short e[8]; } u;
#pragma unroll
    for (int j = 0; j < 8; j++)
      u.e[j] = f2h(cw[(size_t)o * 288 + (size_t)(c0 + j) * 9 + tap]);
    ((s16x8*)wf3)[f * 64 + lane] = u.v;
  }
}

// 1x1 weights [32o][64c] -> 4 fp16 frags
__device__ void dPrepW1x1(const float* __restrict__ wgt, unsigned short* __restrict__ wfb) {
  int tid = threadIdx.x;
  int l = tid & 63, ks = tid >> 6;
  int o = l & 31, kg = l >> 5;
  union { s16x8 v; unsigned short e[8]; } u;
#pragma unroll
  for (int j = 0; j < 8; j++) {
    int c = ks * 16 + kg * 8 + j;
    u.e[j] = f2h(wgt[o * 64 + c]);
  }
  ((s16x8*)wfb)[ks * 64 + l] = u.v;
}

// lw1 [128f][1024k] -> 256 bf16 frags (kFC1m unchanged)
__device__ void dPrepLW(const float* __restrict__ lw1, unsigned short* __restrict__ wfl, int blk) {
  int tid = threadIdx.x;
  int lane = tid & 63, fq = tid >> 6;
  int m = lane & 31, kg = lane >> 5;
  for (int pp = 0; pp < 4; pp++) {
    int f_idx = (blk * 4 + pp) * 4 + fq;
    int ks = f_idx >> 2, nt = f_idx & 3;
    int f = nt * 32 + m;
    int kb = ks * 16 + kg * 8;
    const float4* src = (const float4*)(lw1 + (size_t)f * 1024 + kb);
    float4 v0 = src[0], v1 = src[1];
    float t[8] = {v0.x, v0.y, v0.z, v0.w, v1.x, v1.y, v1.z, v1.w};
    union { s16x8 v; unsigned short e[8]; } u;
#pragma unroll
    for (int j = 0; j < 8; j++) u.e[j] = f2bf(t[j]);
    ((s16x8*)wfl)[f_idx * 64 + lane] = u.v;
  }
}

__global__ __launch_bounds__(256) void kSetup(
    const float* __restrict__ x, float* __restrict__ PX,
    const float* __restrict__ cw1, unsigned short* __restrict__ WF,
    const float* __restrict__ cw3, unsigned short* __restrict__ WF3,
    const float* __restrict__ cw5, unsigned short* __restrict__ WF5,
    const float* __restrict__ cw2, unsigned short* __restrict__ WC2,
    const float* __restrict__ cw4, unsigned short* __restrict__ WC4,
    const float* __restrict__ lw1, unsigned short* __restrict__ WFL) {
  int b = blockIdx.x;
  if (b < 512)       dRedX(x, PX, b);
  else if (b == 512) dPrepW(cw1, WF);
  else if (b == 513) dPrepW3(cw3, WF3);
  else if (b == 514) dPrepW3(cw5, WF5);
  else if (b == 515) dPrepW1x1(cw2, WC2);
  else if (b == 516) dPrepW1x1(cw4, WC4);
  else               dPrepLW(lw1, WFL, b - 517);
}

__global__ __launch_bounds__(256) void kRedPart(const float* __restrict__ part,
                                                float* __restrict__ outp, int nb, int C2) {
  int slot = blockIdx.x;
  int tid = threadIdx.x;
  float s = 0.f;
  for (int i = tid; i < nb; i += 256) s += part[(size_t)i * C2 + slot];
#pragma unroll
  for (int off = 32; off; off >>= 1) s += __shfl_down(s, off);
  __shared__ float ls[4];
  if ((tid & 63) == 0) ls[tid >> 6] = s;
  __syncthreads();
  if (tid == 0) outp[slot] = ls[0] + ls[1] + ls[2] + ls[3];
}

// ---------------------------------------------------------------------------
// kConv1 (MFMA fp16, split): y1 out fp16.
// ---------------------------------------------------------------------------
__global__ __launch_bounds__(256, 2) void kConv1(
    const float* __restrict__ x, const float* __restrict__ cw0,
    const float* __restrict__ bg0, const float* __restrict__ bb0,
    const float* __restrict__ pa0, const unsigned short* __restrict__ wf,
    const float* __restrict__ sx, unsigned short* __restrict__ y1b,
    float* __restrict__ part) {
  __shared__ __align__(16) unsigned short h0t[13440];
  __shared__ __align__(16) float xbuf[420];
  __shared__ float s0[32], t0[32];
  int tid = threadIdx.x;
  int n = blockIdx.x >> 1, half = blockIdx.x & 1;
  int l = tid & 63, w = tid >> 6;
  int nt = w & 1, mpair = w >> 1;
  int m = l & 31, kg = l >> 5;
  int npos = half ? 78 : 91;
  int xoff = half ? 392 : 0;
  int nxpix = half ? 364 : 420;

  f16x8 bfr[9][2];
  const f16x8* wfp = (const f16x8*)wf;
#pragma unroll
  for (int tap = 0; tap < 9; tap++)
#pragma unroll
    for (int kt = 0; kt < 2; kt++)
      bfr[tap][kt] = wfp[(tap * 4 + kt * 2 + nt) * 64 + l];

  {
    int nx4 = half ? 91 : 105;
    if (tid < nx4)
      ((float4*)xbuf)[tid] = ((const float4*)(x + (size_t)n * 784 + xoff))[tid];
  }
  if (tid < 32) {
    const float invM = 1.0f / (4096.0f * 784.0f);
    float mux = sx[0] * invM;
    float varx = fmaxf(sx[1] * invM - mux * mux, 0.0f);
    float w0 = cw0[tid];
    float inv = rsqrtf(w0 * w0 * varx + 1e-5f);
    float sc = w0 * bg0[tid] * inv;
    s0[tid] = sc;
    t0[tid] = bb0[tid] - mux * sc;
  }
  __syncthreads();

  float a0p = *pa0;
  _Float16 a1h = (_Float16)a0p;
  h16x2 a2 = {a1h, a1h};
  h16x2 z2 = {(_Float16)0.0f, (_Float16)0.0f};
  int g = tid & 3;
  h16x2 sg2[4], tg2[4];
#pragma unroll
  for (int j = 0; j < 4; j++) {
    sg2[j] = (h16x2){(_Float16)s0[g * 8 + 2 * j], (_Float16)s0[g * 8 + 2 * j + 1]};
    tg2[j] = (h16x2){(_Float16)t0[g * 8 + 2 * j], (_Float16)t0[g * 8 + 2 * j + 1]};
  }
  char* h0b = (char*)h0t;
  int koffW = g * 16;
  for (int t = 0; t < 7; t++) {
    int p = (tid >> 2) + t * 64;
    if (p < nxpix) {
      _Float16 xh = (_Float16)xbuf[p];
      h16x2 x2 = {xh, xh};
      union { f16x8 v; h16x2 h2[4]; } u;
#pragma unroll
      for (int j = 0; j < 4; j++) {
        h16x2 tv = x2 * sg2[j] + tg2[j];
        u.h2[j] = a2 * __builtin_elementwise_min(tv, z2) +
                  __builtin_elementwise_max(tv, z2);
      }
      int ad = ((p << 6) + koffW) ^ (((p >> 1) & 7) << 4);
      *(f16x8*)(h0b + ad) = u.v;
    }
  }
  __syncthreads();

  int tA = mpair ? 2 : 0;
  int lpA = tA * 32 + m; lpA = lpA > npos - 1 ? npos - 1 : lpA;
  int lpB = 32 + m;      lpB = lpB > npos - 1 ? npos - 1 : lpB;
  int pixbA = (lpA / 13) * 56 + (lpA % 13) * 2;
  int pixbB = (lpB / 13) * 56 + (lpB % 13) * 2;
  int koffA = kg * 16;

#define Z16 {0.f,0.f,0.f,0.f, 0.f,0.f,0.f,0.f, 0.f,0.f,0.f,0.f, 0.f,0.f,0.f,0.f}
  f32x16 acc0 = Z16, acc1 = Z16;

#define MT_STEP(ACC, PB) { \
  _Pragma("unroll") for (int tap = 0; tap < 9; tap++) { \
    int pix = (PB) + (tap / 3) * 28 + (tap % 3); \
    int ad = ((pix << 6) + koffA) ^ (((pix >> 1) & 7) << 4); \
    f16x8 a0 = *(const f16x8*)(h0b + ad); \
    f16x8 a1 = *(const f16x8*)(h0b + (ad ^ 32)); \
    ACC = __builtin_amdgcn_mfma_f32_32x32x16_f16(a0, bfr[tap][0], ACC, 0, 0, 0); \
    ACC = __builtin_amdgcn_mfma_f32_32x32x16_f16(a1, bfr[tap][1], ACC, 0, 0, 0); \
  } }

  MT_STEP(acc0, pixbA)
  if (mpair == 0) { MT_STEP(acc1, pixbB) }
#undef MT_STEP

  __syncthreads();
  unsigned short* ystage = h0t;
  float* sSf = xbuf;
  float* sQf = xbuf + 128;
  float s = 0.f, q = 0.f;
  int och = nt * 32 + m;
#define ST_MT(ACC, TILE) { int pbase = (TILE) * 32 + (kg << 2); \
  _Pragma("unroll") for (int r = 0; r < 16; r++) { \
    int p = pbase + (r & 3) + ((r >> 2) << 3); \
    if (p < npos) { float v = ACC[r]; \
      ystage[p * 64 + och] = f2h(v); s += v; q += v * v; } } }

  ST_MT(acc0, tA)
  if (mpair == 0) { ST_MT(acc1, 1) }
#undef ST_MT

  s += __shfl_xor(s, 32);
  q += __shfl_xor(q, 32);
  if (l < 32) { sSf[w * 32 + l] = s; sQf[w * 32 + l] = q; }
  __syncthreads();
  {
    int nseg = npos * 8;
    const s16x8* src8 = (const s16x8*)ystage;
    s16x8* dst8 = (s16x8*)(y1b + (size_t)n * 10816 + half * 5824);
    for (int e = tid; e < nseg; e += 256) dst8[e] = src8[e];
  }
  if (tid < 64) {
    int o = tid, wv = o >> 5;
    part[(size_t)blockIdx.x * 128 + o] =
        sSf[wv * 32 + (o & 31)] + sSf[(wv + 2) * 32 + (o & 31)];
  } else if (tid < 128) {
    int o = tid - 64, wv = o >> 5;
    part[(size_t)blockIdx.x * 128 + 64 + o] =
        sQf[wv * 32 + (o & 31)] + sQf[(wv + 2) * 32 + (o & 31)];
  }
}

// ---------------------------------------------------------------------------
// kConv1x1m (fp16): [R,64] @ [64,32] -> compact fp16 [R,32].
// ---------------------------------------------------------------------------
__global__ __launch_bounds__(256, 4) void kConv1x1m(
    const unsigned short* __restrict__ wfb, const float* __restrict__ g,
    const float* __restrict__ b, const float* __restrict__ pa,
    const float* __restrict__ stats, float invM,
    const unsigned short* __restrict__ in, unsigned short* __restrict__ outb,
    float* __restrict__ part) {
  __shared__ __align__(16) unsigned short hs[128 * 64];
  __shared__ float scs[64], shs[64];
  __shared__ float sS[4][32], sQ[4][32];
  int tid = threadIdx.x;
  size_t r0 = (size_t)blockIdx.x * 128;
  int l = tid & 63, w = tid >> 6;
  int m = l & 31, kg = l >> 5;

  f16x8 bfr[4];
  const f16x8* bp = (const f16x8*)wfb;
#pragma unroll
  for (int ks = 0; ks < 4; ks++) bfr[ks] = bp[ks * 64 + l];

  if (tid < 64) {
    float mu = stats[tid] * invM;
    float va = fmaxf(stats[64 + tid] * invM - mu * mu, 0.0f);
    float iv = rsqrtf(va + 1e-5f);
    float sc = g[tid] * iv;
    scs[tid] = sc;
    shs[tid] = b[tid] - mu * sc;
  }
  __syncthreads();
  float al = *pa;
  _Float16 alh = (_Float16)al;
  h16x2 a2 = {alh, alh};
  h16x2 z2 = {(_Float16)0.0f, (_Float16)0.0f};
  int seg0 = tid & 7;
  h16x2 sc2[4], sh2[4];
#pragma unroll
  for (int j = 0; j < 4; j++) {
    int c = seg0 * 8 + 2 * j;
    sc2[j] = (h16x2){(_Float16)scs[c], (_Float16)scs[c + 1]};
    sh2[j] = (h16x2){(_Float16)shs[c], (_Float16)shs[c + 1]};
  }
  char* hb = (char*)hs;
#pragma unroll
  for (int i = 0; i < 4; i++) {
    int e = tid + i * 256;
    int row = e >> 3;
    union { f16x8 v; h16x2 h2[4]; } u, o8;
    u.v = *(const f16x8*)(in + (r0 + row) * 64 + seg0 * 8);
#pragma unroll
    for (int j = 0; j < 4; j++) {
      h16x2 tv = u.h2[j] * sc2[j] + sh2[j];
      o8.h2[j] = a2 * __builtin_elementwise_min(tv, z2) +
                 __builtin_elementwise_max(tv, z2);
    }
    int ad = (row * 128 + seg0 * 16) ^ ((row & 7) << 4);
    *(f16x8*)(hb + ad) = o8.v;
  }
  __syncthreads();

#define Z16 {0.f,0.f,0.f,0.f, 0.f,0.f,0.f,0.f, 0.f,0.f,0.f,0.f, 0.f,0.f,0.f,0.f}
  f32x16 acc = Z16;
#undef Z16
  int rloc = w * 32 + m;
  int abase = (rloc * 128 + kg * 16) ^ ((rloc & 7) << 4);
#pragma unroll
  for (int ks = 0; ks < 4; ks++) {
    f16x8 a = *(const f16x8*)(hb + (abase ^ (ks * 32)));
    acc = __builtin_amdgcn_mfma_f32_32x32x16_f16(a, bfr[ks], acc, 0, 0, 0);
  }

  float ss = 0.f, qq = 0.f;
#pragma unroll
  for (int rr = 0; rr < 16; rr++) {
    int rowt = (rr & 3) + ((rr >> 2) << 3) + (kg << 2);
    float v = acc[rr];
    outb[(r0 + (size_t)w * 32 + rowt) * 32 + m] = f2h(v);
    ss += v; qq += v * v;
  }
  ss += __shfl_xor(ss, 32);
  qq += __shfl_xor(qq, 32);
  if (l < 32) { sS[w][l] = ss; sQ[w][l] = qq; }
  __syncthreads();
  if (tid < 32) {
    part[(size_t)blockIdx.x * 64 + tid] = sS[0][tid] + sS[1][tid] + sS[2][tid] + sS[3][tid];
  } else if (tid < 64) {
    int o = tid - 32;
    part[(size_t)blockIdx.x * 64 + 32 + o] = sQ[0][o] + sQ[1][o] + sQ[2][o] + sQ[3][o];
  }
}

// ---------------------------------------------------------------------------
// kConv3m (fp16): input compact fp16 y2 [169][32]; output fp16 y3 [36][64].
// ---------------------------------------------------------------------------
__global__ __launch_bounds__(256, 3) void kConv3m(
    const unsigned short* __restrict__ wf3, const float* __restrict__ g,
    const float* __restrict__ b, const float* __restrict__ pa,
    const float* __restrict__ stats, const unsigned short* __restrict__ in,
    unsigned short* __restrict__ outb, float* __restrict__ part) {
  __shared__ __align__(16) unsigned short h2t[169 * 32];
  __shared__ float scs[32], shs[32];
  __shared__ float sS[4][32], sQ[4][32];
  int tid = threadIdx.x;
  int n = blockIdx.x;
  int l = tid & 63, w = tid >> 6;
  int nt = w & 1, mt = w >> 1;
  int m = l & 31, kg = l >> 5;

  f16x8 bfr[18];
  const f16x8* wfp = (const f16x8*)wf3;
#pragma unroll
  for (int s = 0; s < 18; s++) bfr[s] = wfp[(s * 2 + nt) * 64 + l];

  if (tid < 32) {
    const float invM = 1.0f / 692224.0f;
    float mu = stats[tid] * invM;
    float va = fmaxf(stats[32 + tid] * invM - mu * mu, 0.0f);
    float iv = rsqrtf(va + 1e-5f);
    float sc = g[tid] * iv;
    scs[tid] = sc;
    shs[tid] = b[tid] - mu * sc;
  }
  __syncthreads();
  float al = *pa;
  _Float16 alh = (_Float16)al;
  h16x2 a2 = {alh, alh};
  h16x2 z2 = {(_Float16)0.0f, (_Float16)0.0f};
  int q0 = tid & 3;
  h16x2 sc2[4], sh2[4];
#pragma unroll
  for (int j = 0; j < 4; j++) {
    int c = q0 * 8 + 2 * j;
    sc2[j] = (h16x2){(_Float16)scs[c], (_Float16)scs[c + 1]};
    sh2[j] = (h16x2){(_Float16)shs[c], (_Float16)shs[c + 1]};
  }
  char* hb = (char*)h2t;
  for (int e = tid; e < 676; e += 256) {
    int p = e >> 2;
    union { f16x8 v; h16x2 h2[4]; } u, o8;
    u.v = ((const f16x8*)(in + ((size_t)n * 169 + p) * 32))[q0];
#pragma unroll
    for (int j = 0; j < 4; j++) {
      h16x2 tv = u.h2[j] * sc2[j] + sh2[j];
      o8.h2[j] = a2 * __builtin_elementwise_min(tv, z2) +
                 __builtin_elementwise_max(tv, z2);
    }
    int ad = ((p << 6) + q0 * 16) ^ (((p >> 1) & 7) << 4);
    *(f16x8*)(hb + ad) = o8.v;
  }
  __syncthreads();

  int p = mt * 32 + m;
  p = p > 35 ? 35 : p;
  int pixb = (p / 6) * 26 + (p % 6) * 2;

#define Z16 {0.f,0.f,0.f,0.f, 0.f,0.f,0.f,0.f, 0.f,0.f,0.f,0.f, 0.f,0.f,0.f,0.f}
  f32x16 acc = Z16;
#undef Z16
#pragma unroll
  for (int s = 0; s < 18; s++) {
    int tap = s >> 1;
    int pix = pixb + (tap / 3) * 13 + (tap % 3);
    int ad = ((pix << 6) + (s & 1) * 32 + kg * 16) ^ (((pix >> 1) & 7) << 4);
    f16x8 a = *(const f16x8*)(hb + ad);
    acc = __builtin_amdgcn_mfma_f32_32x32x16_f16(a, bfr[s], acc, 0, 0, 0);
  }

  float ss = 0.f, qq = 0.f;
  int och = nt * 32 + m;
#pragma unroll
  for (int r = 0; r < 16; r++) {
    int row = (r & 3) + ((r >> 2) << 3) + (kg << 2);
    int pp = mt * 32 + row;
    if (pp < 36) {
      float v = acc[r];
      outb[((size_t)n * 36 + pp) * 64 + och] = f2h(v);
      ss += v; qq += v * v;
    }
  }
  ss += __shfl_xor(ss, 32);
  qq += __shfl_xor(qq, 32);
  if (l < 32) { sS[w][l] = ss; sQ[w][l] = qq; }
  __syncthreads();
  if (tid < 64) {
    int o = tid, wv = o >> 5;
    part[(size_t)n * 128 + o] = sS[wv][o & 31] + sS[wv + 2][o & 31];
  } else if (tid < 128) {
    int o = tid - 64, wv = o >> 5;
    part[(size_t)n * 128 + 64 + o] = sQ[wv][o & 31] + sQ[wv + 2][o & 31];
  }
}

// ---------------------------------------------------------------------------
// kConv5m (fp16): M = 2 images x 16 positions; output y5 fp32 k-order.
// ---------------------------------------------------------------------------
__global__ __launch_bounds__(128) void kConv5m(
    const unsigned short* __restrict__ wf5, const float* __restrict__ g,
    const float* __restrict__ b, const float* __restrict__ pa,
    const float* __restrict__ stats, const unsigned short* __restrict__ in,
    float* __restrict__ outb, float* __restrict__ part) {
  __shared__ __align__(16) unsigned short h4t[2 * 1280];
  __shared__ float scs[32], shs[32];
  int tid = threadIdx.x;
  int nA = blockIdx.x * 2;
  int l = tid & 63, w = tid >> 6;
  int m = l & 31, kg = l >> 5;

  f16x8 bfr[18];
  const f16x8* wfp = (const f16x8*)wf5;
#pragma unroll
  for (int s = 0; s < 18; s++) bfr[s] = wfp[(s * 2 + w) * 64 + l];

  if (tid < 32) {
    const float invM = 1.0f / 147456.0f;
    float mu = stats[tid] * invM;
    float va = fmaxf(stats[32 + tid] * invM - mu * mu, 0.0f);
    float iv = rsqrtf(va + 1e-5f);
    float sc = g[tid] * iv;
    scs[tid] = sc;
    shs[tid] = b[tid] - mu * sc;
  }
  __syncthreads();
  float al = *pa;
  _Float16 alh = (_Float16)al;
  h16x2 a2 = {alh, alh};
  h16x2 z2 = {(_Float16)0.0f, (_Float16)0.0f};
  int q0 = tid & 3;
  h16x2 sc2[4], sh2[4];
#pragma unroll
  for (int j = 0; j < 4; j++) {
    int c = q0 * 8 + 2 * j;
    sc2[j] = (h16x2){(_Float16)scs[c], (_Float16)scs[c + 1]};
    sh2[j] = (h16x2){(_Float16)shs[c], (_Float16)shs[c + 1]};
  }
  char* hb = (char*)h4t;
  for (int e = tid; e < 288; e += 128) {
    int img = e >= 144;
    int rem = e - img * 144;
    int p = rem >> 2;
    union { f16x8 v; h16x2 h2[4]; } u, o8;
    u.v = ((const f16x8*)(in + ((size_t)(nA + img) * 36 + p) * 32))[q0];
#pragma unroll
    for (int j = 0; j < 4; j++) {
      h16x2 tv = u.h2[j] * sc2[j] + sh2[j];
      o8.h2[j] = a2 * __builtin_elementwise_min(tv, z2) +
                 __builtin_elementwise_max(tv, z2);
    }
    int ad = img * 2560 + (((p << 6) + q0 * 16) ^ (((p >> 1) & 7) << 4));
    *(f16x8*)(hb + ad) = o8.v;
  }
  __syncthreads();

  int imgl = m >> 4;
  int pl = m & 15;
  int pixb = (pl >> 2) * 6 + (pl & 3);
  int ibase = imgl * 2560;

#define Z16 {0.f,0.f,0.f,0.f, 0.f,0.f,0.f,0.f, 0.f,0.f,0.f,0.f, 0.f,0.f,0.f,0.f}
  f32x16 acc = Z16;
#undef Z16
#pragma unroll
  for (int s = 0; s < 18; s++) {
    int tap = s >> 1;
    int pix = pixb + (tap / 3) * 6 + (tap % 3);
    int ad = ibase + (((pix << 6) + (s & 1) * 32 + kg * 16) ^ (((pix >> 1) & 7) << 4));
    f16x8 a = *(const f16x8*)(hb + ad);
    acc = __builtin_amdgcn_mfma_f32_32x32x16_f16(a, bfr[s], acc, 0, 0, 0);
  }

  float ss = 0.f, qq = 0.f;
  int och = w * 32 + m;
#pragma unroll
  for (int r = 0; r < 16; r++) {
    int row = (r & 3) + ((r >> 2) << 3) + (kg << 2);
    int img = row >> 4, p = row & 15;
    float v = acc[r];
    outb[(size_t)(nA + img) * 1024 + och * 16 + p] = v;
    ss += v; qq += v * v;
  }
  ss += __shfl_xor(ss, 32);
  qq += __shfl_xor(qq, 32);
  if (l < 32) {
    part[(size_t)blockIdx.x * 128 + w * 32 + l] = ss;
    part[(size_t)blockIdx.x * 128 + 64 + w * 32 + l] = qq;
  }
}

// ---------------------------------------------------------------------------
// kFC1m: fp32 y5 -> bf16 staged GEMM.
// ---------------------------------------------------------------------------
__global__ __launch_bounds__(128) void kFC1m(
    const unsigned short* __restrict__ wfl, const float* __restrict__ g,
    const float* __restrict__ b, const float* __restrict__ pa,
    const float* __restrict__ stats, const float* __restrict__ y5,
    float* __restrict__ z, float* __restrict__ part) {
  __shared__ __align__(16) unsigned short hs[32 * 1024];
  __shared__ float scs[64], shs[64];
  int tid = threadIdx.x;
  int n0 = blockIdx.x * 32;
  if (tid < 64) {
    const float invM = 1.0f / 65536.0f;
    float mu = stats[tid] * invM;
    float va = fmaxf(stats[64 + tid] * invM - mu * mu, 0.0f);
    float iv = rsqrtf(va + 1e-5f);
    float sc = g[tid] * iv;
    scs[tid] = sc;
    shs[tid] = b[tid] - mu * sc;
  }
  __syncthreads();
  float al = *pa;
  char* hb = (char*)hs;
  for (int i = 0; i < 32; i++) {
    int sgi = tid + i * 128;
    int nn = sgi >> 7, k8 = sgi & 127;
    int c = k8 >> 1;
    float sc = scs[c], sh = shs[c];
    const float4* src = (const float4*)(y5 + (size_t)(n0 + nn) * 1024 + k8 * 8);
    float4 v0 = src[0], v1 = src[1];
    float t[8] = {v0.x, v0.y, v0.z, v0.w, v1.x, v1.y, v1.z, v1.w};
    union { s16x8 v; unsigned short e[8]; } u;
#pragma unroll
    for (int j = 0; j < 8; j++) {
      float h = fmaf(t[j], sc, sh);
      h = h > 0.f ? h : al * h;
      u.e[j] = f2bf(h);
    }
    int ad = (nn * 2048 + k8 * 16) ^ ((nn & 7) << 4);
    *(s16x8*)(hb + ad) = u.v;
  }
  __syncthreads();

  int l = tid & 63, w = tid >> 6;
  int m = l & 31, kg = l >> 5;
#define Z16 {0.f,0.f,0.f,0.f, 0.f,0.f,0.f,0.f, 0.f,0.f,0.f,0.f, 0.f,0.f,0.f,0.f}
  f32x16 acc0 = Z16, acc1 = Z16;
#undef Z16
  const s16x8* bp = (const s16x8*)wfl;
  int abase = (m * 2048 + kg * 16) ^ ((m & 7) << 4);
#pragma unroll 4
  for (int ks = 0; ks < 64; ks++) {
    s16x8 a = *(const s16x8*)(hb + (abase ^ (ks * 32)));
    s16x8 b0 = bp[(ks * 4 + 2 * w + 0) * 64 + l];
    s16x8 b1 = bp[(ks * 4 + 2 * w + 1) * 64 + l];
    acc0 = __builtin_amdgcn_mfma_f32_32x32x16_bf16(a, b0, acc0, 0, 0, 0);
    acc1 = __builtin_amdgcn_mfma_f32_32x32x16_bf16(a, b1, acc1, 0, 0, 0);
  }

  float s0 = 0.f, q0 = 0.f, s1 = 0.f, q1 = 0.f;
  int f0c = (2 * w) * 32 + m, f1c = (2 * w + 1) * 32 + m;
#pragma unroll
  for (int r = 0; r < 16; r++) {
    int n = (r & 3) + ((r >> 2) << 3) + (kg << 2);
    float v0 = acc0[r], v1 = acc1[r];
    z[(size_t)(n0 + n) * 128 + f0c] = v0;
    z[(size_t)(n0 + n) * 128 + f1c] = v1;
    s0 += v0; q0 += v0 * v0; s1 += v1; q1 += v1 * v1;
  }
  s0 += __shfl_xor(s0, 32); q0 += __shfl_xor(q0, 32);
  s1 += __shfl_xor(s1, 32); q1 += __shfl_xor(q1, 32);
  if (l < 32) {
    size_t base = (size_t)blockIdx.x * 256;
    part[base + w * 64 + m] = s0;
    part[base + w * 64 + 32 + m] = s1;
    part[base + 128 + w * 64 + m] = q0;
    part[base + 128 + w * 64 + 32 + m] = q1;
  }
}

// ---------------------------------------------------------------------------
__global__ __launch_bounds__(256) void kFC2Arc(
    const float* __restrict__ z, const float* __restrict__ s6,
    const float* __restrict__ lg1, const float* __restrict__ lb1,
    const float* __restrict__ pl1, const float* __restrict__ lw2,
    const float* __restrict__ lb2, const float* __restrict__ aw,
    const int* __restrict__ labels, float* __restrict__ out,
    float* __restrict__ lpart) {
  __shared__ float scz[128], shz[128], w2a[128], w2b[128];
  __shared__ float awl[20];
  __shared__ float lred[4];
  int tid = threadIdx.x;
  if (tid < 128) {
    const float invM = 1.0f / 4096.0f;
    float mu = s6[tid] * invM;
    float va = fmaxf(s6[128 + tid] * invM - mu * mu, 0.0f);
    float iv = rsqrtf(va + 1e-5f);
    float sc = lg1[tid] * iv;
    scz[tid] = sc;
    shz[tid] = lb1[tid] - mu * sc;
    w2a[tid] = lw2[tid];
    w2b[tid] = lw2[128 + tid];
  }
  if (tid < 20) awl[tid] = aw[tid];
  __syncthreads();
  float al = *pl1;
  int n = blockIdx.x * 256 + tid;
  const float4* zr = (const float4*)(z + (size_t)n * 128);
  float f0 = lb2[0], f1 = lb2[1];
#pragma unroll
  for (int kb = 0; kb < 32; kb++) {
    float4 v = zr[kb];
    float hv[4] = {v.x, v.y, v.z, v.w};
#pragma unroll
    for (int u = 0; u < 4; u++) {
      int k = kb * 4 + u;
      float h = fmaf(hv[u], scz[k], shz[k]);
      h = h > 0.f ? h : al * h;
      f0 = fmaf(h, w2a[k], f0);
      f1 = fmaf(h, w2b[k], f1);
    }
  }
  out[(size_t)n * 2] = f0;
  out[(size_t)n * 2 + 1] = f1;
  float nrm = sqrtf(fmaxf(f0 * f0 + f1 * f1, 1e-30f));
  float xn0 = f0 / nrm, xn1 = f1 / nrm;
  int lab = labels[n];
  float wv[10];
  float m64 = -3.4e38f;
#pragma unroll
  for (int j = 0; j < 10; j++) {
    float w = xn0 * awl[2 * j] + xn1 * awl[2 * j + 1];
    wv[j] = w;
    out[8192 + (size_t)n * 10 + j] = w;
    m64 = fmaxf(m64, 64.0f * w);
  }
  float tgt = wv[0];
#pragma unroll
  for (int j = 1; j < 10; j++) if (j == lab) tgt = wv[j];
  if (lab == 0) tgt = wv[0];
  const float CLO = (float)(-1.0 + 1e-7);
  const float CHI = (float)(1.0 - 1e-7);
  float t = fminf(fmaxf(tgt, CLO), CHI);
  float num = 64.0f * (t * 0.87758256189037276f - 0.47942553860420301f * sqrtf(fmaxf(1.0f - t * t, 0.0f)));
  float L = fmaxf(num, m64);
  float dsum = expf(num - L) - expf(64.0f * tgt - L);
#pragma unroll
  for (int j = 0; j < 10; j++) dsum += expf(64.0f * wv[j] - L);
  dsum = fmaxf(dsum, 1e-30f);
  float li = num - (L + logf(dsum));
#pragma unroll
  for (int off = 32; off; off >>= 1) li += __shfl_down(li, off);
  if ((tid & 63) == 0) lred[tid >> 6] = li;
  __syncthreads();
  if (tid == 0) lpart[blockIdx.x] = lred[0] + lred[1] + lred[2] + lred[3];
}

__global__ void kFinal(const float* __restrict__ lpart, float* __restrict__ out) {
  int tid = threadIdx.x;
  float v = (tid < 16) ? lpart[tid] : 0.f;
#pragma unroll
  for (int off = 8; off; off >>= 1) v += __shfl_down(v, off);
  if (tid == 0) out[49152] = -v * (1.0f / 4096.0f);
}

// ---------------------------------------------------------------------------
extern "C" void kernel_launch(void* const* d_in, const int* in_sizes, int n_in,
                              void* d_out, int out_size, void* d_ws, size_t ws_size,
                              hipStream_t stream) {
  const float* x   = (const float*)d_in[0];
  const int* labels = (const int*)d_in[1];
  const float* cw0 = (const float*)d_in[2];
  const float* bg0 = (const float*)d_in[3];
  const float* bb0 = (const float*)d_in[4];
  const float* pa0 = (const float*)d_in[5];
  const float* cw1 = (const float*)d_in[6];
  const float* bg1 = (const float*)d_in[7];
  const float* bb1 = (const float*)d_in[8];
  const float* pa1 = (const float*)d_in[9];
  const float* cw2 = (const float*)d_in[10];
  const float* bg2 = (const float*)d_in[11];
  const float* bb2 = (const float*)d_in[12];
  const float* pa2 = (const float*)d_in[13];
  const float* cw3 = (const float*)d_in[14];
  const float* bg3 = (const float*)d_in[15];
  const float* bb3 = (const float*)d_in[16];
  const float* pa3 = (const float*)d_in[17];
  const float* cw4 = (const float*)d_in[18];
  const float* bg4 = (const float*)d_in[19];
  const float* bb4 = (const float*)d_in[20];
  const float* pa4 = (const float*)d_in[21];
  const float* cw5 = (const float*)d_in[22];
  const float* bg5 = (const float*)d_in[23];
  const float* bb5 = (const float*)d_in[24];
  const float* pa5 = (const float*)d_in[25];
  const float* lw1 = (const float*)d_in[26];
  const float* lg1 = (const float*)d_in[27];
  const float* lb1 = (const float*)d_in[28];
  const float* pl1 = (const float*)d_in[29];
  const float* lw2 = (const float*)d_in[30];
  const float* lb2 = (const float*)d_in[31];
  const float* aw  = (const float*)d_in[32];
  float* out = (float*)d_out;
  float* ws = (float*)d_ws;

  float* PX = ws;                    // 1024
  float* SX = ws + 1024;             // 2
  float* S1 = ws + 1040;             // 128
  float* S2 = ws + 1168;             // 64
  float* S3 = ws + 1232;             // 128
  float* S4 = ws + 1360;             // 64
  float* S5 = ws + 1424;             // 128
  float* S6 = ws + 1552;             // 256
  float* LP = ws + 1808;             // 16
  float* P1 = ws + 2048;             // [8192][128] = 1048576
  float* P2 = P1 + 1048576;          // [5408][64]  = 346112
  float* P3 = P2 + 346112;           // [4096][128] = 524288
  float* P4 = P3 + 524288;           // [1152][64]  = 73728
  float* P5 = P4 + 73728;            // [2048][128] = 262144
  float* P6 = P1;                    // [128][256] — aliases dead P1
  unsigned short* Y1 = (unsigned short*)(ws + (size_t)2359296);  // [4096][169][64] fp16
  unsigned short* Y2 = Y1 + (size_t)44302336;  // [4096][169][32] fp16
  unsigned short* Y3 = Y2 + (size_t)22151168;  // [4096][36][64] fp16
  unsigned short* Y4 = Y3 + (size_t)9437184;   // [4096][36][32] fp16
  float* Y5 = (float*)(Y4 + (size_t)4718592);  // [4096][1024] fp32 k-order
  float* Z  = Y5 + (size_t)4194304;  // [4096][128]
  float* WF = Z + 524288;            // conv1 weight frags (fp16)
  float* WFL = WF + 16384;           // lw1 frags (bf16, 256 KB)
  float* WF3 = WFL + 65536;          // conv3 weight frags (fp16)
  float* WC2 = WF3 + 16384;          // conv2 1x1 frags (fp16)
  float* WC4 = WC2 + 1024;           // conv4 1x1 frags (fp16)
  float* WF5 = WC4 + 1024;           // conv5 weight frags (fp16)

  kSetup<<<533, 256, 0, stream>>>(x, PX, cw1, (unsigned short*)WF,
                                  cw3, (unsigned short*)WF3,
                                  cw5, (unsigned short*)WF5,
                                  cw2, (unsigned short*)WC2,
                                  cw4, (unsigned short*)WC4,
                                  lw1, (unsigned short*)WFL);
  kRedPart<<<2, 256, 0, stream>>>(PX, SX, 512, 2);
  kConv1<<<8192, 256, 0, stream>>>(x, cw0, bg0, bb0, pa0, (const unsigned short*)WF, SX, Y1, P1);
  kRedPart<<<128, 256, 0, stream>>>(P1, S1, 8192, 128);
  kConv1x1m<<<5408, 256, 0, stream>>>((const unsigned short*)WC2, bg1, bb1, pa1, S1,
                                      1.0f / 692224.0f, Y1, Y2, P2);
  kRedPart<<<64, 256, 0, stream>>>(P2, S2, 5408, 64);
  kConv3m<<<4096, 256, 0, stream>>>((const unsigned short*)WF3, bg2, bb2, pa2, S2, Y2, Y3, P3);
  kRedPart<<<128, 256, 0, stream>>>(P3, S3, 4096, 128);
  kConv1x1m<<<1152, 256, 0, stream>>>((const unsigned short*)WC4, bg3, bb3, pa3, S3,
                                      1.0f / 147456.0f, Y3, Y4, P4);
  kRedPart<<<64, 256, 0, stream>>>(P4, S4, 1152, 64);
  kConv5m<<<2048, 128, 0, stream>>>((const unsigned short*)WF5, bg4, bb4, pa4, S4, Y4, Y5, P5);
  kRedPart<<<128, 256, 0, stream>>>(P5, S5, 2048, 128);
  kFC1m<<<128, 128, 0, stream>>>((const unsigned short*)WFL, bg5, bb5, pa5, S5, Y5, Z, P6);
  kRedPart<<<256, 256, 0, stream>>>(P6, S6, 128, 256);
  kFC2Arc<<<16, 256, 0, stream>>>(Z, S6, lg1, lb1, pl1, lw2, lb2, aw, labels, out, LP);
  kFinal<<<1, 64, 0, stream>>>(LP, out);
}

// Round 19
// 202.353 us; speedup vs baseline: 25.6277x; 1.0334x over previous
//
#include <hip/hip_runtime.h>
#include <hip/hip_bf16.h>
#include <hip/hip_fp16.h>
#include <math.h>

// ---------------------------------------------------------------------------
// R19 (base R18/R16): (1) 1x1 convs drop LDS staging entirely: A-fragments
// loaded directly from global (row-major [R][64] IS the fragment layout;
// lane (m,kg) reads 16B at row*64+ks*16+kg*8), BN+PReLU applied in-register
// with packed fp16 scales. (2) kFC1m same direct-load treatment, y5 -> fp16
// (BN channel for k-step ks is exactly ks -> scalar broadcast scale), WFL fp16,
// grid 128->256 (n x f-half split). (3) PX->SX reduce folded into kConv1
// (plain per-block 4KB L2 read, NO atomics - the safe piece of R17): -1 launch.
// ---------------------------------------------------------------------------

typedef __attribute__((ext_vector_type(8))) short s16x8;
typedef __attribute__((ext_vector_type(8))) _Float16 f16x8;
typedef __attribute__((ext_vector_type(2))) _Float16 h16x2;
typedef __attribute__((ext_vector_type(16))) float f32x16;

__device__ __forceinline__ unsigned short f2bf(float f) {
  __hip_bfloat16 h = __float2bfloat16(f);
  unsigned short u;
  __builtin_memcpy(&u, &h, 2);
  return u;
}
__device__ __forceinline__ float bf2f(unsigned short h) {
  union { unsigned int u; float f; } t; t.u = ((unsigned int)h) << 16; return t.f;
}
__device__ __forceinline__ unsigned short f2h(float f) {
  _Float16 h = (_Float16)f;
  unsigned short u;
  __builtin_memcpy(&u, &h, 2);
  return u;
}

// ---------------------------------------------------------------------------
// Setup device bodies
// ---------------------------------------------------------------------------
__device__ void dRedX(const float* __restrict__ x, float* __restrict__ part, int b) {
  int tid = threadIdx.x;
  const float4* x4 = (const float4*)x;
  float s = 0.f, q = 0.f;
  for (size_t i = (size_t)b * 256 + tid; i < 802816; i += (size_t)512 * 256) {
    float4 v = x4[i];
    s += v.x + v.y + v.z + v.w;
    q += v.x * v.x + v.y * v.y + v.z * v.z + v.w * v.w;
  }
#pragma unroll
  for (int off = 32; off; off >>= 1) {
    s += __shfl_down(s, off);
    q += __shfl_down(q, off);
  }
  __shared__ float ls[4][2];
  int w = tid >> 6;
  if ((tid & 63) == 0) { ls[w][0] = s; ls[w][1] = q; }
  __syncthreads();
  if (tid == 0) {
    part[b * 2]     = ls[0][0] + ls[1][0] + ls[2][0] + ls[3][0];
    part[b * 2 + 1] = ls[0][1] + ls[1][1] + ls[2][1] + ls[3][1];
  }
}

__device__ void dPrepW(const float* __restrict__ cw1, unsigned short* __restrict__ wf) {
  int tid = threadIdx.x;
  int lane = tid & 63, fb = tid >> 6;
  int m = lane & 31, kg = lane >> 5;
  for (int pass = 0; pass < 9; pass++) {
    int f = pass * 4 + fb;
    int tap = f >> 2, rem = f & 3, kt = rem >> 1, nt = rem & 1;
    int o = nt * 32 + m;
    int kb = kt * 16 + kg * 8;
    union { s16x8 v; unsigned short e[8]; } u;
#pragma unroll
    for (int j = 0; j < 8; j++)
      u.e[j] = f2h(cw1[(size_t)o * 288 + (size_t)(kb + j) * 9 + tap]);
    ((s16x8*)wf)[f * 64 + lane] = u.v;
  }
}

__device__ void dPrepW3(const float* __restrict__ cw, unsigned short* __restrict__ wf3) {
  int tid = threadIdx.x;
  int lane = tid & 63, fq = tid >> 6;
  int m = lane & 31, kg = lane >> 5;
  for (int pass = 0; pass < 9; pass++) {
    int f = pass * 4 + fq;
    int s = f >> 1, nt = f & 1;
    int tap = s >> 1;
    int o = nt * 32 + m;
    int c0 = (s & 1) * 16 + kg * 8;
    union { s16x8 v; unsigned short e[8]; } u;
#pragma unroll
    for (int j = 0; j < 8; j++)
      u.e[j] = f2h(cw[(size_t)o * 288 + (size_t)(c0 + j) * 9 + tap]);
    ((s16x8*)wf3)[f * 64 + lane] = u.v;
  }
}

__device__ void dPrepW1x1(const float* __restrict__ wgt, unsigned short* __restrict__ wfb) {
  int tid = threadIdx.x;
  int l = tid & 63, ks = tid >> 6;
  int o = l & 31, kg = l >> 5;
  union { s16x8 v; unsigned short e[8]; } u;
#pragma unroll
  for (int j = 0; j < 8; j++) {
    int c = ks * 16 + kg * 8 + j;
    u.e[j] = f2h(wgt[o * 64 + c]);
  }
  ((s16x8*)wfb)[ks * 64 + l] = u.v;
}

// lw1 [128f][1024k] -> 256 fp16 frags
__device__ void dPrepLW(const float* __restrict__ lw1, unsigned short* __restrict__ wfl, int blk) {
  int tid = threadIdx.x;
  int lane = tid & 63, fq = tid >> 6;
  int m = lane & 31, kg = lane >> 5;
  for (int pp = 0; pp < 4; pp++) {
    int f_idx = (blk * 4 + pp) * 4 + fq;
    int ks = f_idx >> 2, nt = f_idx & 3;
    int f = nt * 32 + m;
    int kb = ks * 16 + kg * 8;
    const float4* src = (const float4*)(lw1 + (size_t)f * 1024 + kb);
    float4 v0 = src[0], v1 = src[1];
    float t[8] = {v0.x, v0.y, v0.z, v0.w, v1.x, v1.y, v1.z, v1.w};
    union { s16x8 v; unsigned short e[8]; } u;
#pragma unroll
    for (int j = 0; j < 8; j++) u.e[j] = f2h(t[j]);
    ((s16x8*)wfl)[f_idx * 64 + lane] = u.v;
  }
}

__global__ __launch_bounds__(256) void kSetup(
    const float* __restrict__ x, float* __restrict__ PX,
    const float* __restrict__ cw1, unsigned short* __restrict__ WF,
    const float* __restrict__ cw3, unsigned short* __restrict__ WF3,
    const float* __restrict__ cw5, unsigned short* __restrict__ WF5,
    const float* __restrict__ cw2, unsigned short* __restrict__ WC2,
    const float* __restrict__ cw4, unsigned short* __restrict__ WC4,
    const float* __restrict__ lw1, unsigned short* __restrict__ WFL) {
  int b = blockIdx.x;
  if (b < 512)       dRedX(x, PX, b);
  else if (b == 512) dPrepW(cw1, WF);
  else if (b == 513) dPrepW3(cw3, WF3);
  else if (b == 514) dPrepW3(cw5, WF5);
  else if (b == 515) dPrepW1x1(cw2, WC2);
  else if (b == 516) dPrepW1x1(cw4, WC4);
  else               dPrepLW(lw1, WFL, b - 517);
}

__global__ __launch_bounds__(256) void kRedPart(const float* __restrict__ part,
                                                float* __restrict__ outp, int nb, int C2) {
  int slot = blockIdx.x;
  int tid = threadIdx.x;
  float s = 0.f;
  for (int i = tid; i < nb; i += 256) s += part[(size_t)i * C2 + slot];
#pragma unroll
  for (int off = 32; off; off >>= 1) s += __shfl_down(s, off);
  __shared__ float ls[4];
  if ((tid & 63) == 0) ls[tid >> 6] = s;
  __syncthreads();
  if (tid == 0) outp[slot] = ls[0] + ls[1] + ls[2] + ls[3];
}

// ---------------------------------------------------------------------------
// kConv1 (MFMA fp16, split): PX reduced per-block (no atomics); y1 out fp16.
// ---------------------------------------------------------------------------
__global__ __launch_bounds__(256, 2) void kConv1(
    const float* __restrict__ x, const float* __restrict__ cw0,
    const float* __restrict__ bg0, const float* __restrict__ bb0,
    const float* __restrict__ pa0, const unsigned short* __restrict__ wf,
    const float* __restrict__ PX, unsigned short* __restrict__ y1b,
    float* __restrict__ part) {
  __shared__ __align__(16) unsigned short h0t[13440];
  __shared__ __align__(16) float xbuf[420];
  __shared__ float s0[32], t0[32];
  __shared__ float sxr[8];
  int tid = threadIdx.x;
  int n = blockIdx.x >> 1, half = blockIdx.x & 1;
  int l = tid & 63, w = tid >> 6;
  int nt = w & 1, mpair = w >> 1;
  int m = l & 31, kg = l >> 5;
  int npos = half ? 78 : 91;
  int xoff = half ? 392 : 0;
  int nxpix = half ? 364 : 420;

  f16x8 bfr[9][2];
  const f16x8* wfp = (const f16x8*)wf;
#pragma unroll
  for (int tap = 0; tap < 9; tap++)
#pragma unroll
    for (int kt = 0; kt < 2; kt++)
      bfr[tap][kt] = wfp[(tap * 4 + kt * 2 + nt) * 64 + l];

  {
    int nx4 = half ? 91 : 105;
    if (tid < nx4)
      ((float4*)xbuf)[tid] = ((const float4*)(x + (size_t)n * 784 + xoff))[tid];
  }
  // PX reduce (512 pairs): each thread covers i=tid and i=tid+256
  {
    float rs = PX[tid * 2]     + PX[(tid + 256) * 2];
    float rq = PX[tid * 2 + 1] + PX[(tid + 256) * 2 + 1];
#pragma unroll
    for (int off = 32; off; off >>= 1) {
      rs += __shfl_down(rs, off);
      rq += __shfl_down(rq, off);
    }
    if ((tid & 63) == 0) { sxr[(tid >> 6) * 2] = rs; sxr[(tid >> 6) * 2 + 1] = rq; }
  }
  __syncthreads();
  if (tid < 32) {
    float sxs = sxr[0] + sxr[2] + sxr[4] + sxr[6];
    float sxq = sxr[1] + sxr[3] + sxr[5] + sxr[7];
    const float invM = 1.0f / (4096.0f * 784.0f);
    float mux = sxs * invM;
    float varx = fmaxf(sxq * invM - mux * mux, 0.0f);
    float w0 = cw0[tid];
    float inv = rsqrtf(w0 * w0 * varx + 1e-5f);
    float sc = w0 * bg0[tid] * inv;
    s0[tid] = sc;
    t0[tid] = bb0[tid] - mux * sc;
  }
  __syncthreads();

  float a0p = *pa0;
  _Float16 a1h = (_Float16)a0p;
  h16x2 a2 = {a1h, a1h};
  h16x2 z2 = {(_Float16)0.0f, (_Float16)0.0f};
  int g = tid & 3;
  h16x2 sg2[4], tg2[4];
#pragma unroll
  for (int j = 0; j < 4; j++) {
    sg2[j] = (h16x2){(_Float16)s0[g * 8 + 2 * j], (_Float16)s0[g * 8 + 2 * j + 1]};
    tg2[j] = (h16x2){(_Float16)t0[g * 8 + 2 * j], (_Float16)t0[g * 8 + 2 * j + 1]};
  }
  char* h0b = (char*)h0t;
  int koffW = g * 16;
  for (int t = 0; t < 7; t++) {
    int p = (tid >> 2) + t * 64;
    if (p < nxpix) {
      _Float16 xh = (_Float16)xbuf[p];
      h16x2 x2 = {xh, xh};
      union { f16x8 v; h16x2 h2[4]; } u;
#pragma unroll
      for (int j = 0; j < 4; j++) {
        h16x2 tv = x2 * sg2[j] + tg2[j];
        u.h2[j] = a2 * __builtin_elementwise_min(tv, z2) +
                  __builtin_elementwise_max(tv, z2);
      }
      int ad = ((p << 6) + koffW) ^ (((p >> 1) & 7) << 4);
      *(f16x8*)(h0b + ad) = u.v;
    }
  }
  __syncthreads();

  int tA = mpair ? 2 : 0;
  int lpA = tA * 32 + m; lpA = lpA > npos - 1 ? npos - 1 : lpA;
  int lpB = 32 + m;      lpB = lpB > npos - 1 ? npos - 1 : lpB;
  int pixbA = (lpA / 13) * 56 + (lpA % 13) * 2;
  int pixbB = (lpB / 13) * 56 + (lpB % 13) * 2;
  int koffA = kg * 16;

#define Z16 {0.f,0.f,0.f,0.f, 0.f,0.f,0.f,0.f, 0.f,0.f,0.f,0.f, 0.f,0.f,0.f,0.f}
  f32x16 acc0 = Z16, acc1 = Z16;

#define MT_STEP(ACC, PB) { \
  _Pragma("unroll") for (int tap = 0; tap < 9; tap++) { \
    int pix = (PB) + (tap / 3) * 28 + (tap % 3); \
    int ad = ((pix << 6) + koffA) ^ (((pix >> 1) & 7) << 4); \
    f16x8 a0 = *(const f16x8*)(h0b + ad); \
    f16x8 a1 = *(const f16x8*)(h0b + (ad ^ 32)); \
    ACC = __builtin_amdgcn_mfma_f32_32x32x16_f16(a0, bfr[tap][0], ACC, 0, 0, 0); \
    ACC = __builtin_amdgcn_mfma_f32_32x32x16_f16(a1, bfr[tap][1], ACC, 0, 0, 0); \
  } }

  MT_STEP(acc0, pixbA)
  if (mpair == 0) { MT_STEP(acc1, pixbB) }
#undef MT_STEP

  __syncthreads();
  unsigned short* ystage = h0t;
  float* sSf = xbuf;
  float* sQf = xbuf + 128;
  float s = 0.f, q = 0.f;
  int och = nt * 32 + m;
#define ST_MT(ACC, TILE) { int pbase = (TILE) * 32 + (kg << 2); \
  _Pragma("unroll") for (int r = 0; r < 16; r++) { \
    int p = pbase + (r & 3) + ((r >> 2) << 3); \
    if (p < npos) { float v = ACC[r]; \
      ystage[p * 64 + och] = f2h(v); s += v; q += v * v; } } }

  ST_MT(acc0, tA)
  if (mpair == 0) { ST_MT(acc1, 1) }
#undef ST_MT

  s += __shfl_xor(s, 32);
  q += __shfl_xor(q, 32);
  if (l < 32) { sSf[w * 32 + l] = s; sQf[w * 32 + l] = q; }
  __syncthreads();
  {
    int nseg = npos * 8;
    const s16x8* src8 = (const s16x8*)ystage;
    s16x8* dst8 = (s16x8*)(y1b + (size_t)n * 10816 + half * 5824);
    for (int e = tid; e < nseg; e += 256) dst8[e] = src8[e];
  }
  if (tid < 64) {
    int o = tid, wv = o >> 5;
    part[(size_t)blockIdx.x * 128 + o] =
        sSf[wv * 32 + (o & 31)] + sSf[(wv + 2) * 32 + (o & 31)];
  } else if (tid < 128) {
    int o = tid - 64, wv = o >> 5;
    part[(size_t)blockIdx.x * 128 + 64 + o] =
        sQf[wv * 32 + (o & 31)] + sQf[(wv + 2) * 32 + (o & 31)];
  }
}

// ---------------------------------------------------------------------------
// kConv1x1m (fp16, LDS-free): A-fragments loaded directly from global
// (row-major [R][64] IS the fragment layout), BN+PReLU in-register.
// ---------------------------------------------------------------------------
__global__ __launch_bounds__(256, 4) void kConv1x1m(
    const unsigned short* __restrict__ wfb, const float* __restrict__ g,
    const float* __restrict__ b, const float* __restrict__ pa,
    const float* __restrict__ stats, float invM,
    const unsigned short* __restrict__ in, unsigned short* __restrict__ outb,
    float* __restrict__ part) {
  __shared__ float scs[64], shs[64];
  __shared__ float sS[4][32], sQ[4][32];
  int tid = threadIdx.x;
  size_t r0 = (size_t)blockIdx.x * 128;
  int l = tid & 63, w = tid >> 6;
  int m = l & 31, kg = l >> 5;

  f16x8 bfr[4];
  const f16x8* bp = (const f16x8*)wfb;
#pragma unroll
  for (int ks = 0; ks < 4; ks++) bfr[ks] = bp[ks * 64 + l];

  if (tid < 64) {
    float mu = stats[tid] * invM;
    float va = fmaxf(stats[64 + tid] * invM - mu * mu, 0.0f);
    float iv = rsqrtf(va + 1e-5f);
    float sc = g[tid] * iv;
    scs[tid] = sc;
    shs[tid] = b[tid] - mu * sc;
  }
  __syncthreads();
  float al = *pa;
  _Float16 alh = (_Float16)al;
  h16x2 a2 = {alh, alh};
  h16x2 z2 = {(_Float16)0.0f, (_Float16)0.0f};
  // per-lane scale regs: k = ks*16 + kg*8 + 2j(,+1)
  h16x2 sc2[4][4], sh2[4][4];
#pragma unroll
  for (int ks = 0; ks < 4; ks++)
#pragma unroll
    for (int j = 0; j < 4; j++) {
      int c = ks * 16 + kg * 8 + 2 * j;
      sc2[ks][j] = (h16x2){(_Float16)scs[c], (_Float16)scs[c + 1]};
      sh2[ks][j] = (h16x2){(_Float16)shs[c], (_Float16)shs[c + 1]};
    }

  int rloc = w * 32 + m;
  const f16x8* arow = (const f16x8*)(in + (r0 + rloc) * 64);

#define Z16 {0.f,0.f,0.f,0.f, 0.f,0.f,0.f,0.f, 0.f,0.f,0.f,0.f, 0.f,0.f,0.f,0.f}
  f32x16 acc = Z16;
#undef Z16
#pragma unroll
  for (int ks = 0; ks < 4; ks++) {
    union { f16x8 v; h16x2 h2[4]; } ui, ua;
    ui.v = arow[ks * 2 + kg];
#pragma unroll
    for (int j = 0; j < 4; j++) {
      h16x2 tv = ui.h2[j] * sc2[ks][j] + sh2[ks][j];
      ua.h2[j] = a2 * __builtin_elementwise_min(tv, z2) +
                 __builtin_elementwise_max(tv, z2);
    }
    acc = __builtin_amdgcn_mfma_f32_32x32x16_f16(ua.v, bfr[ks], acc, 0, 0, 0);
  }

  float ss = 0.f, qq = 0.f;
#pragma unroll
  for (int rr = 0; rr < 16; rr++) {
    int rowt = (rr & 3) + ((rr >> 2) << 3) + (kg << 2);
    float v = acc[rr];
    outb[(r0 + (size_t)w * 32 + rowt) * 32 + m] = f2h(v);
    ss += v; qq += v * v;
  }
  ss += __shfl_xor(ss, 32);
  qq += __shfl_xor(qq, 32);
  if (l < 32) { sS[w][l] = ss; sQ[w][l] = qq; }
  __syncthreads();
  if (tid < 32) {
    part[(size_t)blockIdx.x * 64 + tid] = sS[0][tid] + sS[1][tid] + sS[2][tid] + sS[3][tid];
  } else if (tid < 64) {
    int o = tid - 32;
    part[(size_t)blockIdx.x * 64 + 32 + o] = sQ[0][o] + sQ[1][o] + sQ[2][o] + sQ[3][o];
  }
}

// ---------------------------------------------------------------------------
// kConv3m (fp16): unchanged from R18 (LDS staging justified: 9x reuse).
// ---------------------------------------------------------------------------
__global__ __launch_bounds__(256, 3) void kConv3m(
    const unsigned short* __restrict__ wf3, const float* __restrict__ g,
    const float* __restrict__ b, const float* __restrict__ pa,
    const float* __restrict__ stats, const unsigned short* __restrict__ in,
    unsigned short* __restrict__ outb, float* __restrict__ part) {
  __shared__ __align__(16) unsigned short h2t[169 * 32];
  __shared__ float scs[32], shs[32];
  __shared__ float sS[4][32], sQ[4][32];
  int tid = threadIdx.x;
  int n = blockIdx.x;
  int l = tid & 63, w = tid >> 6;
  int nt = w & 1, mt = w >> 1;
  int m = l & 31, kg = l >> 5;

  f16x8 bfr[18];
  const f16x8* wfp = (const f16x8*)wf3;
#pragma unroll
  for (int s = 0; s < 18; s++) bfr[s] = wfp[(s * 2 + nt) * 64 + l];

  if (tid < 32) {
    const float invM = 1.0f / 692224.0f;
    float mu = stats[tid] * invM;
    float va = fmaxf(stats[32 + tid] * invM - mu * mu, 0.0f);
    float iv = rsqrtf(va + 1e-5f);
    float sc = g[tid] * iv;
    scs[tid] = sc;
    shs[tid] = b[tid] - mu * sc;
  }
  __syncthreads();
  float al = *pa;
  _Float16 alh = (_Float16)al;
  h16x2 a2 = {alh, alh};
  h16x2 z2 = {(_Float16)0.0f, (_Float16)0.0f};
  int q0 = tid & 3;
  h16x2 sc2[4], sh2[4];
#pragma unroll
  for (int j = 0; j < 4; j++) {
    int c = q0 * 8 + 2 * j;
    sc2[j] = (h16x2){(_Float16)scs[c], (_Float16)scs[c + 1]};
    sh2[j] = (h16x2){(_Float16)shs[c], (_Float16)shs[c + 1]};
  }
  char* hb = (char*)h2t;
  for (int e = tid; e < 676; e += 256) {
    int p = e >> 2;
    union { f16x8 v; h16x2 h2[4]; } u, o8;
    u.v = ((const f16x8*)(in + ((size_t)n * 169 + p) * 32))[q0];
#pragma unroll
    for (int j = 0; j < 4; j++) {
      h16x2 tv = u.h2[j] * sc2[j] + sh2[j];
      o8.h2[j] = a2 * __builtin_elementwise_min(tv, z2) +
                 __builtin_elementwise_max(tv, z2);
    }
    int ad = ((p << 6) + q0 * 16) ^ (((p >> 1) & 7) << 4);
    *(f16x8*)(hb + ad) = o8.v;
  }
  __syncthreads();

  int p = mt * 32 + m;
  p = p > 35 ? 35 : p;
  int pixb = (p / 6) * 26 + (p % 6) * 2;

#define Z16 {0.f,0.f,0.f,0.f, 0.f,0.f,0.f,0.f, 0.f,0.f,0.f,0.f, 0.f,0.f,0.f,0.f}
  f32x16 acc = Z16;
#undef Z16
#pragma unroll
  for (int s = 0; s < 18; s++) {
    int tap = s >> 1;
    int pix = pixb + (tap / 3) * 13 + (tap % 3);
    int ad = ((pix << 6) + (s & 1) * 32 + kg * 16) ^ (((pix >> 1) & 7) << 4);
    f16x8 a = *(const f16x8*)(hb + ad);
    acc = __builtin_amdgcn_mfma_f32_32x32x16_f16(a, bfr[s], acc, 0, 0, 0);
  }

  float ss = 0.f, qq = 0.f;
  int och = nt * 32 + m;
#pragma unroll
  for (int r = 0; r < 16; r++) {
    int row = (r & 3) + ((r >> 2) << 3) + (kg << 2);
    int pp = mt * 32 + row;
    if (pp < 36) {
      float v = acc[r];
      outb[((size_t)n * 36 + pp) * 64 + och] = f2h(v);
      ss += v; qq += v * v;
    }
  }
  ss += __shfl_xor(ss, 32);
  qq += __shfl_xor(qq, 32);
  if (l < 32) { sS[w][l] = ss; sQ[w][l] = qq; }
  __syncthreads();
  if (tid < 64) {
    int o = tid, wv = o >> 5;
    part[(size_t)n * 128 + o] = sS[wv][o & 31] + sS[wv + 2][o & 31];
  } else if (tid < 128) {
    int o = tid - 64, wv = o >> 5;
    part[(size_t)n * 128 + 64 + o] = sQ[wv][o & 31] + sQ[wv + 2][o & 31];
  }
}

// ---------------------------------------------------------------------------
// kConv5m (fp16): y5 out now fp16 k-order [n][och*16+p].
// ---------------------------------------------------------------------------
__global__ __launch_bounds__(128) void kConv5m(
    const unsigned short* __restrict__ wf5, const float* __restrict__ g,
    const float* __restrict__ b, const float* __restrict__ pa,
    const float* __restrict__ stats, const unsigned short* __restrict__ in,
    unsigned short* __restrict__ outb, float* __restrict__ part) {
  __shared__ __align__(16) unsigned short h4t[2 * 1280];
  __shared__ float scs[32], shs[32];
  int tid = threadIdx.x;
  int nA = blockIdx.x * 2;
  int l = tid & 63, w = tid >> 6;
  int m = l & 31, kg = l >> 5;

  f16x8 bfr[18];
  const f16x8* wfp = (const f16x8*)wf5;
#pragma unroll
  for (int s = 0; s < 18; s++) bfr[s] = wfp[(s * 2 + w) * 64 + l];

  if (tid < 32) {
    const float invM = 1.0f / 147456.0f;
    float mu = stats[tid] * invM;
    float va = fmaxf(stats[32 + tid] * invM - mu * mu, 0.0f);
    float iv = rsqrtf(va + 1e-5f);
    float sc = g[tid] * iv;
    scs[tid] = sc;
    shs[tid] = b[tid] - mu * sc;
  }
  __syncthreads();
  float al = *pa;
  _Float16 alh = (_Float16)al;
  h16x2 a2 = {alh, alh};
  h16x2 z2 = {(_Float16)0.0f, (_Float16)0.0f};
  int q0 = tid & 3;
  h16x2 sc2[4], sh2[4];
#pragma unroll
  for (int j = 0; j < 4; j++) {
    int c = q0 * 8 + 2 * j;
    sc2[j] = (h16x2){(_Float16)scs[c], (_Float16)scs[c + 1]};
    sh2[j] = (h16x2){(_Float16)shs[c], (_Float16)shs[c + 1]};
  }
  char* hb = (char*)h4t;
  for (int e = tid; e < 288; e += 128) {
    int img = e >= 144;
    int rem = e - img * 144;
    int p = rem >> 2;
    union { f16x8 v; h16x2 h2[4]; } u, o8;
    u.v = ((const f16x8*)(in + ((size_t)(nA + img) * 36 + p) * 32))[q0];
#pragma unroll
    for (int j = 0; j < 4; j++) {
      h16x2 tv = u.h2[j] * sc2[j] + sh2[j];
      o8.h2[j] = a2 * __builtin_elementwise_min(tv, z2) +
                 __builtin_elementwise_max(tv, z2);
    }
    int ad = img * 2560 + (((p << 6) + q0 * 16) ^ (((p >> 1) & 7) << 4));
    *(f16x8*)(hb + ad) = o8.v;
  }
  __syncthreads();

  int imgl = m >> 4;
  int pl = m & 15;
  int pixb = (pl >> 2) * 6 + (pl & 3);
  int ibase = imgl * 2560;

#define Z16 {0.f,0.f,0.f,0.f, 0.f,0.f,0.f,0.f, 0.f,0.f,0.f,0.f, 0.f,0.f,0.f,0.f}
  f32x16 acc = Z16;
#undef Z16
#pragma unroll
  for (int s = 0; s < 18; s++) {
    int tap = s >> 1;
    int pix = pixb + (tap / 3) * 6 + (tap % 3);
    int ad = ibase + (((pix << 6) + (s & 1) * 32 + kg * 16) ^ (((pix >> 1) & 7) << 4));
    f16x8 a = *(const f16x8*)(hb + ad);
    acc = __builtin_amdgcn_mfma_f32_32x32x16_f16(a, bfr[s], acc, 0, 0, 0);
  }

  float ss = 0.f, qq = 0.f;
  int och = w * 32 + m;
#pragma unroll
  for (int r = 0; r < 16; r++) {
    int row = (r & 3) + ((r >> 2) << 3) + (kg << 2);
    int img = row >> 4, p = row & 15;
    float v = acc[r];
    outb[(size_t)(nA + img) * 1024 + och * 16 + p] = f2h(v);
    ss += v; qq += v * v;
  }
  ss += __shfl_xor(ss, 32);
  qq += __shfl_xor(qq, 32);
  if (l < 32) {
    part[(size_t)blockIdx.x * 128 + w * 32 + l] = ss;
    part[(size_t)blockIdx.x * 128 + 64 + w * 32 + l] = qq;
  }
}

// ---------------------------------------------------------------------------
// kFC1m (fp16, LDS-free): grid 256 = (nb, f-half). A-frags direct from y5
// (k-order rows ARE fragment layout); BN channel for k-step ks is ks exactly
// -> scalar broadcast scale per iteration. Partials: P6[nb][256]:
// cols f -> sums, 128+f -> sq (the two f-half blocks fill disjoint columns).
// ---------------------------------------------------------------------------
__global__ __launch_bounds__(128) void kFC1m(
    const unsigned short* __restrict__ wfl, const float* __restrict__ g,
    const float* __restrict__ b, const float* __restrict__ pa,
    const float* __restrict__ stats, const unsigned short* __restrict__ y5,
    float* __restrict__ z, float* __restrict__ part) {
  __shared__ float scs[64], shs[64];
  int tid = threadIdx.x;
  int nb = blockIdx.x >> 1, fh = blockIdx.x & 1;
  int n0 = nb * 32;
  int l = tid & 63, w = tid >> 6;
  int m = l & 31, kg = l >> 5;
  if (tid < 64) {
    const float invM = 1.0f / 65536.0f;
    float mu = stats[tid] * invM;
    float va = fmaxf(stats[64 + tid] * invM - mu * mu, 0.0f);
    float iv = rsqrtf(va + 1e-5f);
    float sc = g[tid] * iv;
    scs[tid] = sc;
    shs[tid] = b[tid] - mu * sc;
  }
  __syncthreads();
  float al = *pa;
  _Float16 alh = (_Float16)al;
  h16x2 a2 = {alh, alh};
  h16x2 z2 = {(_Float16)0.0f, (_Float16)0.0f};
  int t = fh * 2 + w;
  const f16x8* bp = (const f16x8*)wfl;
  const f16x8* arow = (const f16x8*)(y5 + (size_t)(n0 + m) * 1024);

#define Z16 {0.f,0.f,0.f,0.f, 0.f,0.f,0.f,0.f, 0.f,0.f,0.f,0.f, 0.f,0.f,0.f,0.f}
  f32x16 acc = Z16;
#undef Z16
#pragma unroll 4
  for (int ks = 0; ks < 64; ks++) {
    _Float16 sch = (_Float16)scs[ks];
    _Float16 shh = (_Float16)shs[ks];
    h16x2 sc2 = {sch, sch};
    h16x2 sh2 = {shh, shh};
    union { f16x8 v; h16x2 h2[4]; } ui, ua;
    ui.v = arow[ks * 2 + kg];
#pragma unroll
    for (int j = 0; j < 4; j++) {
      h16x2 tv = ui.h2[j] * sc2 + sh2;
      ua.h2[j] = a2 * __builtin_elementwise_min(tv, z2) +
                 __builtin_elementwise_max(tv, z2);
    }
    f16x8 bv = bp[(ks * 4 + t) * 64 + l];
    acc = __builtin_amdgcn_mfma_f32_32x32x16_f16(ua.v, bv, acc, 0, 0, 0);
  }

  float s0 = 0.f, q0 = 0.f;
  int f = fh * 64 + w * 32 + m;
#pragma unroll
  for (int r = 0; r < 16; r++) {
    int n = (r & 3) + ((r >> 2) << 3) + (kg << 2);
    float v = acc[r];
    z[(size_t)(n0 + n) * 128 + f] = v;
    s0 += v; q0 += v * v;
  }
  s0 += __shfl_xor(s0, 32);
  q0 += __shfl_xor(q0, 32);
  if (l < 32) {
    size_t base = (size_t)nb * 256;
    part[base + fh * 64 + w * 32 + l] = s0;
    part[base + 128 + fh * 64 + w * 32 + l] = q0;
  }
}

// ---------------------------------------------------------------------------
__global__ __launch_bounds__(256) void kFC2Arc(
    const float* __restrict__ z, const float* __restrict__ s6,
    const float* __restrict__ lg1, const float* __restrict__ lb1,
    const float* __restrict__ pl1, const float* __restrict__ lw2,
    const float* __restrict__ lb2, const float* __restrict__ aw,
    const int* __restrict__ labels, float* __restrict__ out,
    float* __restrict__ lpart) {
  __shared__ float scz[128], shz[128], w2a[128], w2b[128];
  __shared__ float awl[20];
  __shared__ float lred[4];
  int tid = threadIdx.x;
  if (tid < 128) {
    const float invM = 1.0f / 4096.0f;
    float mu = s6[tid] * invM;
    float va = fmaxf(s6[128 + tid] * invM - mu * mu, 0.0f);
    float iv = rsqrtf(va + 1e-5f);
    float sc = lg1[tid] * iv;
    scz[tid] = sc;
    shz[tid] = lb1[tid] - mu * sc;
    w2a[tid] = lw2[tid];
    w2b[tid] = lw2[128 + tid];
  }
  if (tid < 20) awl[tid] = aw[tid];
  __syncthreads();
  float al = *pl1;
  int n = blockIdx.x * 256 + tid;
  const float4* zr = (const float4*)(z + (size_t)n * 128);
  float f0 = lb2[0], f1 = lb2[1];
#pragma unroll
  for (int kb = 0; kb < 32; kb++) {
    float4 v = zr[kb];
    float hv[4] = {v.x, v.y, v.z, v.w};
#pragma unroll
    for (int u = 0; u < 4; u++) {
      int k = kb * 4 + u;
      float h = fmaf(hv[u], scz[k], shz[k]);
      h = h > 0.f ? h : al * h;
      f0 = fmaf(h, w2a[k], f0);
      f1 = fmaf(h, w2b[k], f1);
    }
  }
  out[(size_t)n * 2] = f0;
  out[(size_t)n * 2 + 1] = f1;
  float nrm = sqrtf(fmaxf(f0 * f0 + f1 * f1, 1e-30f));
  float xn0 = f0 / nrm, xn1 = f1 / nrm;
  int lab = labels[n];
  float wv[10];
  float m64 = -3.4e38f;
#pragma unroll
  for (int j = 0; j < 10; j++) {
    float w = xn0 * awl[2 * j] + xn1 * awl[2 * j + 1];
    wv[j] = w;
    out[8192 + (size_t)n * 10 + j] = w;
    m64 = fmaxf(m64, 64.0f * w);
  }
  float tgt = wv[0];
#pragma unroll
  for (int j = 1; j < 10; j++) if (j == lab) tgt = wv[j];
  if (lab == 0) tgt = wv[0];
  const float CLO = (float)(-1.0 + 1e-7);
  const float CHI = (float)(1.0 - 1e-7);
  float t = fminf(fmaxf(tgt, CLO), CHI);
  float num = 64.0f * (t * 0.87758256189037276f - 0.47942553860420301f * sqrtf(fmaxf(1.0f - t * t, 0.0f)));
  float L = fmaxf(num, m64);
  float dsum = expf(num - L) - expf(64.0f * tgt - L);
#pragma unroll
  for (int j = 0; j < 10; j++) dsum += expf(64.0f * wv[j] - L);
  dsum = fmaxf(dsum, 1e-30f);
  float li = num - (L + logf(dsum));
#pragma unroll
  for (int off = 32; off; off >>= 1) li += __shfl_down(li, off);
  if ((tid & 63) == 0) lred[tid >> 6] = li;
  __syncthreads();
  if (tid == 0) lpart[blockIdx.x] = lred[0] + lred[1] + lred[2] + lred[3];
}

__global__ void kFinal(const float* __restrict__ lpart, float* __restrict__ out) {
  int tid = threadIdx.x;
  float v = (tid < 16) ? lpart[tid] : 0.f;
#pragma unroll
  for (int off = 8; off; off >>= 1) v += __shfl_down(v, off);
  if (tid == 0) out[49152] = -v * (1.0f / 4096.0f);
}

// ---------------------------------------------------------------------------
extern "C" void kernel_launch(void* const* d_in, const int* in_sizes, int n_in,
                              void* d_out, int out_size, void* d_ws, size_t ws_size,
                              hipStream_t stream) {
  const float* x   = (const float*)d_in[0];
  const int* labels = (const int*)d_in[1];
  const float* cw0 = (const float*)d_in[2];
  const float* bg0 = (const float*)d_in[3];
  const float* bb0 = (const float*)d_in[4];
  const float* pa0 = (const float*)d_in[5];
  const float* cw1 = (const float*)d_in[6];
  const float* bg1 = (const float*)d_in[7];
  const float* bb1 = (const float*)d_in[8];
  const float* pa1 = (const float*)d_in[9];
  const float* cw2 = (const float*)d_in[10];
  const float* bg2 = (const float*)d_in[11];
  const float* bb2 = (const float*)d_in[12];
  const float* pa2 = (const float*)d_in[13];
  const float* cw3 = (const float*)d_in[14];
  const float* bg3 = (const float*)d_in[15];
  const float* bb3 = (const float*)d_in[16];
  const float* pa3 = (const float*)d_in[17];
  const float* cw4 = (const float*)d_in[18];
  const float* bg4 = (const float*)d_in[19];
  const float* bb4 = (const float*)d_in[20];
  const float* pa4 = (const float*)d_in[21];
  const float* cw5 = (const float*)d_in[22];
  const float* bg5 = (const float*)d_in[23];
  const float* bb5 = (const float*)d_in[24];
  const float* pa5 = (const float*)d_in[25];
  const float* lw1 = (const float*)d_in[26];
  const float* lg1 = (const float*)d_in[27];
  const float* lb1 = (const float*)d_in[28];
  const float* pl1 = (const float*)d_in[29];
  const float* lw2 = (const float*)d_in[30];
  const float* lb2 = (const float*)d_in[31];
  const float* aw  = (const float*)d_in[32];
  float* out = (float*)d_out;
  float* ws = (float*)d_ws;

  float* PX = ws;                    // 1024
  float* S1 = ws + 1040;             // 128
  float* S2 = ws + 1168;             // 64
  float* S3 = ws + 1232;             // 128
  float* S4 = ws + 1360;             // 64
  float* S5 = ws + 1424;             // 128
  float* S6 = ws + 1552;             // 256
  float* LP = ws + 1808;             // 16
  float* P1 = ws + 2048;             // [8192][128] = 1048576
  float* P2 = P1 + 1048576;          // [5408][64]  = 346112
  float* P3 = P2 + 346112;           // [4096][128] = 524288
  float* P4 = P3 + 524288;           // [1152][64]  = 73728
  float* P5 = P4 + 73728;            // [2048][128] = 262144
  float* P6 = P1;                    // [128][256] — aliases dead P1
  unsigned short* Y1 = (unsigned short*)(ws + (size_t)2359296);  // [4096][169][64] fp16
  unsigned short* Y2 = Y1 + (size_t)44302336;  // [4096][169][32] fp16
  unsigned short* Y3 = Y2 + (size_t)22151168;  // [4096][36][64] fp16
  unsigned short* Y4 = Y3 + (size_t)9437184;   // [4096][36][32] fp16
  unsigned short* Y5 = Y4 + (size_t)4718592;   // [4096][1024] fp16 k-order
  float* Z  = (float*)(Y5 + (size_t)4194304);  // [4096][128] fp32
  float* WF = Z + 524288;            // conv1 weight frags (fp16)
  float* WFL = WF + 16384;           // lw1 frags (fp16)
  float* WF3 = WFL + 65536;          // conv3 weight frags (fp16)
  float* WC2 = WF3 + 16384;          // conv2 1x1 frags (fp16)
  float* WC4 = WC2 + 1024;           // conv4 1x1 frags (fp16)
  float* WF5 = WC4 + 1024;           // conv5 weight frags (fp16)

  kSetup<<<533, 256, 0, stream>>>(x, PX, cw1, (unsigned short*)WF,
                                  cw3, (unsigned short*)WF3,
                                  cw5, (unsigned short*)WF5,
                                  cw2, (unsigned short*)WC2,
                                  cw4, (unsigned short*)WC4,
                                  lw1, (unsigned short*)WFL);
  kConv1<<<8192, 256, 0, stream>>>(x, cw0, bg0, bb0, pa0, (const unsigned short*)WF,
                                   PX, Y1, P1);
  kRedPart<<<128, 256, 0, stream>>>(P1, S1, 8192, 128);
  kConv1x1m<<<5408, 256, 0, stream>>>((const unsigned short*)WC2, bg1, bb1, pa1, S1,
                                      1.0f / 692224.0f, Y1, Y2, P2);
  kRedPart<<<64, 256, 0, stream>>>(P2, S2, 5408, 64);
  kConv3m<<<4096, 256, 0, stream>>>((const unsigned short*)WF3, bg2, bb2, pa2, S2, Y2, Y3, P3);
  kRedPart<<<128, 256, 0, stream>>>(P3, S3, 4096, 128);
  kConv1x1m<<<1152, 256, 0, stream>>>((const unsigned short*)WC4, bg3, bb3, pa3, S3,
                                      1.0f / 147456.0f, Y3, Y4, P4);
  kRedPart<<<64, 256, 0, stream>>>(P4, S4, 1152, 64);
  kConv5m<<<2048, 128, 0, stream>>>((const unsigned short*)WF5, bg4, bb4, pa4, S4, Y4, Y5, P5);
  kRedPart<<<128, 256, 0, stream>>>(P5, S5, 2048, 128);
  kFC1m<<<256, 128, 0, stream>>>((const unsigned short*)WFL, bg5, bb5, pa5, S5, Y5, Z, P6);
  kRedPart<<<256, 256, 0, stream>>>(P6, S6, 128, 256);
  kFC2Arc<<<16, 256, 0, stream>>>(Z, S6, lg1, lb1, pl1, lw2, lb2, aw, labels, out, LP);
  kFinal<<<1, 64, 0, stream>>>(LP, out);
}

// Round 20
// 200.793 us; speedup vs baseline: 25.8268x; 1.0078x over previous
//
#include <hip/hip_runtime.h>
#include <hip/hip_bf16.h>
#include <hip/hip_fp16.h>
#include <math.h>

// ---------------------------------------------------------------------------
// R20 = R19 with the PX-fold reverted (it cost kConv1 +5us for a -2.5us launch
// saving). kConv1 is byte-identical to R18's verified version (separate SX
// reduce; VGPR 60). Keeps R19's wins: LDS-free 1x1 convs, LDS-free fp16 kFC1m,
// fp16 y5/WFL.
// ---------------------------------------------------------------------------

typedef __attribute__((ext_vector_type(8))) short s16x8;
typedef __attribute__((ext_vector_type(8))) _Float16 f16x8;
typedef __attribute__((ext_vector_type(2))) _Float16 h16x2;
typedef __attribute__((ext_vector_type(16))) float f32x16;

__device__ __forceinline__ unsigned short f2bf(float f) {
  __hip_bfloat16 h = __float2bfloat16(f);
  unsigned short u;
  __builtin_memcpy(&u, &h, 2);
  return u;
}
__device__ __forceinline__ float bf2f(unsigned short h) {
  union { unsigned int u; float f; } t; t.u = ((unsigned int)h) << 16; return t.f;
}
__device__ __forceinline__ unsigned short f2h(float f) {
  _Float16 h = (_Float16)f;
  unsigned short u;
  __builtin_memcpy(&u, &h, 2);
  return u;
}

// ---------------------------------------------------------------------------
// Setup device bodies
// ---------------------------------------------------------------------------
__device__ void dRedX(const float* __restrict__ x, float* __restrict__ part, int b) {
  int tid = threadIdx.x;
  const float4* x4 = (const float4*)x;
  float s = 0.f, q = 0.f;
  for (size_t i = (size_t)b * 256 + tid; i < 802816; i += (size_t)512 * 256) {
    float4 v = x4[i];
    s += v.x + v.y + v.z + v.w;
    q += v.x * v.x + v.y * v.y + v.z * v.z + v.w * v.w;
  }
#pragma unroll
  for (int off = 32; off; off >>= 1) {
    s += __shfl_down(s, off);
    q += __shfl_down(q, off);
  }
  __shared__ float ls[4][2];
  int w = tid >> 6;
  if ((tid & 63) == 0) { ls[w][0] = s; ls[w][1] = q; }
  __syncthreads();
  if (tid == 0) {
    part[b * 2]     = ls[0][0] + ls[1][0] + ls[2][0] + ls[3][0];
    part[b * 2 + 1] = ls[0][1] + ls[1][1] + ls[2][1] + ls[3][1];
  }
}

__device__ void dPrepW(const float* __restrict__ cw1, unsigned short* __restrict__ wf) {
  int tid = threadIdx.x;
  int lane = tid & 63, fb = tid >> 6;
  int m = lane & 31, kg = lane >> 5;
  for (int pass = 0; pass < 9; pass++) {
    int f = pass * 4 + fb;
    int tap = f >> 2, rem = f & 3, kt = rem >> 1, nt = rem & 1;
    int o = nt * 32 + m;
    int kb = kt * 16 + kg * 8;
    union { s16x8 v; unsigned short e[8]; } u;
#pragma unroll
    for (int j = 0; j < 8; j++)
      u.e[j] = f2h(cw1[(size_t)o * 288 + (size_t)(kb + j) * 9 + tap]);
    ((s16x8*)wf)[f * 64 + lane] = u.v;
  }
}

__device__ void dPrepW3(const float* __restrict__ cw, unsigned short* __restrict__ wf3) {
  int tid = threadIdx.x;
  int lane = tid & 63, fq = tid >> 6;
  int m = lane & 31, kg = lane >> 5;
  for (int pass = 0; pass < 9; pass++) {
    int f = pass * 4 + fq;
    int s = f >> 1, nt = f & 1;
    int tap = s >> 1;
    int o = nt * 32 + m;
    int c0 = (s & 1) * 16 + kg * 8;
    union { s16x8 v; unsigned short e[8]; } u;
#pragma unroll
    for (int j = 0; j < 8; j++)
      u.e[j] = f2h(cw[(size_t)o * 288 + (size_t)(c0 + j) * 9 + tap]);
    ((s16x8*)wf3)[f * 64 + lane] = u.v;
  }
}

__device__ void dPrepW1x1(const float* __restrict__ wgt, unsigned short* __restrict__ wfb) {
  int tid = threadIdx.x;
  int l = tid & 63, ks = tid >> 6;
  int o = l & 31, kg = l >> 5;
  union { s16x8 v; unsigned short e[8]; } u;
#pragma unroll
  for (int j = 0; j < 8; j++) {
    int c = ks * 16 + kg * 8 + j;
    u.e[j] = f2h(wgt[o * 64 + c]);
  }
  ((s16x8*)wfb)[ks * 64 + l] = u.v;
}

// lw1 [128f][1024k] -> 256 fp16 frags
__device__ void dPrepLW(const float* __restrict__ lw1, unsigned short* __restrict__ wfl, int blk) {
  int tid = threadIdx.x;
  int lane = tid & 63, fq = tid >> 6;
  int m = lane & 31, kg = lane >> 5;
  for (int pp = 0; pp < 4; pp++) {
    int f_idx = (blk * 4 + pp) * 4 + fq;
    int ks = f_idx >> 2, nt = f_idx & 3;
    int f = nt * 32 + m;
    int kb = ks * 16 + kg * 8;
    const float4* src = (const float4*)(lw1 + (size_t)f * 1024 + kb);
    float4 v0 = src[0], v1 = src[1];
    float t[8] = {v0.x, v0.y, v0.z, v0.w, v1.x, v1.y, v1.z, v1.w};
    union { s16x8 v; unsigned short e[8]; } u;
#pragma unroll
    for (int j = 0; j < 8; j++) u.e[j] = f2h(t[j]);
    ((s16x8*)wfl)[f_idx * 64 + lane] = u.v;
  }
}

__global__ __launch_bounds__(256) void kSetup(
    const float* __restrict__ x, float* __restrict__ PX,
    const float* __restrict__ cw1, unsigned short* __restrict__ WF,
    const float* __restrict__ cw3, unsigned short* __restrict__ WF3,
    const float* __restrict__ cw5, unsigned short* __restrict__ WF5,
    const float* __restrict__ cw2, unsigned short* __restrict__ WC2,
    const float* __restrict__ cw4, unsigned short* __restrict__ WC4,
    const float* __restrict__ lw1, unsigned short* __restrict__ WFL) {
  int b = blockIdx.x;
  if (b < 512)       dRedX(x, PX, b);
  else if (b == 512) dPrepW(cw1, WF);
  else if (b == 513) dPrepW3(cw3, WF3);
  else if (b == 514) dPrepW3(cw5, WF5);
  else if (b == 515) dPrepW1x1(cw2, WC2);
  else if (b == 516) dPrepW1x1(cw4, WC4);
  else               dPrepLW(lw1, WFL, b - 517);
}

__global__ __launch_bounds__(256) void kRedPart(const float* __restrict__ part,
                                                float* __restrict__ outp, int nb, int C2) {
  int slot = blockIdx.x;
  int tid = threadIdx.x;
  float s = 0.f;
  for (int i = tid; i < nb; i += 256) s += part[(size_t)i * C2 + slot];
#pragma unroll
  for (int off = 32; off; off >>= 1) s += __shfl_down(s, off);
  __shared__ float ls[4];
  if ((tid & 63) == 0) ls[tid >> 6] = s;
  __syncthreads();
  if (tid == 0) outp[slot] = ls[0] + ls[1] + ls[2] + ls[3];
}

// ---------------------------------------------------------------------------
// kConv1 (MFMA fp16, split): y1 out fp16. (R18-verified version: sx param.)
// ---------------------------------------------------------------------------
__global__ __launch_bounds__(256, 2) void kConv1(
    const float* __restrict__ x, const float* __restrict__ cw0,
    const float* __restrict__ bg0, const float* __restrict__ bb0,
    const float* __restrict__ pa0, const unsigned short* __restrict__ wf,
    const float* __restrict__ sx, unsigned short* __restrict__ y1b,
    float* __restrict__ part) {
  __shared__ __align__(16) unsigned short h0t[13440];
  __shared__ __align__(16) float xbuf[420];
  __shared__ float s0[32], t0[32];
  int tid = threadIdx.x;
  int n = blockIdx.x >> 1, half = blockIdx.x & 1;
  int l = tid & 63, w = tid >> 6;
  int nt = w & 1, mpair = w >> 1;
  int m = l & 31, kg = l >> 5;
  int npos = half ? 78 : 91;
  int xoff = half ? 392 : 0;
  int nxpix = half ? 364 : 420;

  f16x8 bfr[9][2];
  const f16x8* wfp = (const f16x8*)wf;
#pragma unroll
  for (int tap = 0; tap < 9; tap++)
#pragma unroll
    for (int kt = 0; kt < 2; kt++)
      bfr[tap][kt] = wfp[(tap * 4 + kt * 2 + nt) * 64 + l];

  {
    int nx4 = half ? 91 : 105;
    if (tid < nx4)
      ((float4*)xbuf)[tid] = ((const float4*)(x + (size_t)n * 784 + xoff))[tid];
  }
  if (tid < 32) {
    const float invM = 1.0f / (4096.0f * 784.0f);
    float mux = sx[0] * invM;
    float varx = fmaxf(sx[1] * invM - mux * mux, 0.0f);
    float w0 = cw0[tid];
    float inv = rsqrtf(w0 * w0 * varx + 1e-5f);
    float sc = w0 * bg0[tid] * inv;
    s0[tid] = sc;
    t0[tid] = bb0[tid] - mux * sc;
  }
  __syncthreads();

  float a0p = *pa0;
  _Float16 a1h = (_Float16)a0p;
  h16x2 a2 = {a1h, a1h};
  h16x2 z2 = {(_Float16)0.0f, (_Float16)0.0f};
  int g = tid & 3;
  h16x2 sg2[4], tg2[4];
#pragma unroll
  for (int j = 0; j < 4; j++) {
    sg2[j] = (h16x2){(_Float16)s0[g * 8 + 2 * j], (_Float16)s0[g * 8 + 2 * j + 1]};
    tg2[j] = (h16x2){(_Float16)t0[g * 8 + 2 * j], (_Float16)t0[g * 8 + 2 * j + 1]};
  }
  char* h0b = (char*)h0t;
  int koffW = g * 16;
  for (int t = 0; t < 7; t++) {
    int p = (tid >> 2) + t * 64;
    if (p < nxpix) {
      _Float16 xh = (_Float16)xbuf[p];
      h16x2 x2 = {xh, xh};
      union { f16x8 v; h16x2 h2[4]; } u;
#pragma unroll
      for (int j = 0; j < 4; j++) {
        h16x2 tv = x2 * sg2[j] + tg2[j];
        u.h2[j] = a2 * __builtin_elementwise_min(tv, z2) +
                  __builtin_elementwise_max(tv, z2);
      }
      int ad = ((p << 6) + koffW) ^ (((p >> 1) & 7) << 4);
      *(f16x8*)(h0b + ad) = u.v;
    }
  }
  __syncthreads();

  int tA = mpair ? 2 : 0;
  int lpA = tA * 32 + m; lpA = lpA > npos - 1 ? npos - 1 : lpA;
  int lpB = 32 + m;      lpB = lpB > npos - 1 ? npos - 1 : lpB;
  int pixbA = (lpA / 13) * 56 + (lpA % 13) * 2;
  int pixbB = (lpB / 13) * 56 + (lpB % 13) * 2;
  int koffA = kg * 16;

#define Z16 {0.f,0.f,0.f,0.f, 0.f,0.f,0.f,0.f, 0.f,0.f,0.f,0.f, 0.f,0.f,0.f,0.f}
  f32x16 acc0 = Z16, acc1 = Z16;

#define MT_STEP(ACC, PB) { \
  _Pragma("unroll") for (int tap = 0; tap < 9; tap++) { \
    int pix = (PB) + (tap / 3) * 28 + (tap % 3); \
    int ad = ((pix << 6) + koffA) ^ (((pix >> 1) & 7) << 4); \
    f16x8 a0 = *(const f16x8*)(h0b + ad); \
    f16x8 a1 = *(const f16x8*)(h0b + (ad ^ 32)); \
    ACC = __builtin_amdgcn_mfma_f32_32x32x16_f16(a0, bfr[tap][0], ACC, 0, 0, 0); \
    ACC = __builtin_amdgcn_mfma_f32_32x32x16_f16(a1, bfr[tap][1], ACC, 0, 0, 0); \
  } }

  MT_STEP(acc0, pixbA)
  if (mpair == 0) { MT_STEP(acc1, pixbB) }
#undef MT_STEP

  __syncthreads();
  unsigned short* ystage = h0t;
  float* sSf = xbuf;
  float* sQf = xbuf + 128;
  float s = 0.f, q = 0.f;
  int och = nt * 32 + m;
#define ST_MT(ACC, TILE) { int pbase = (TILE) * 32 + (kg << 2); \
  _Pragma("unroll") for (int r = 0; r < 16; r++) { \
    int p = pbase + (r & 3) + ((r >> 2) << 3); \
    if (p < npos) { float v = ACC[r]; \
      ystage[p * 64 + och] = f2h(v); s += v; q += v * v; } } }

  ST_MT(acc0, tA)
  if (mpair == 0) { ST_MT(acc1, 1) }
#undef ST_MT

  s += __shfl_xor(s, 32);
  q += __shfl_xor(q, 32);
  if (l < 32) { sSf[w * 32 + l] = s; sQf[w * 32 + l] = q; }
  __syncthreads();
  {
    int nseg = npos * 8;
    const s16x8* src8 = (const s16x8*)ystage;
    s16x8* dst8 = (s16x8*)(y1b + (size_t)n * 10816 + half * 5824);
    for (int e = tid; e < nseg; e += 256) dst8[e] = src8[e];
  }
  if (tid < 64) {
    int o = tid, wv = o >> 5;
    part[(size_t)blockIdx.x * 128 + o] =
        sSf[wv * 32 + (o & 31)] + sSf[(wv + 2) * 32 + (o & 31)];
  } else if (tid < 128) {
    int o = tid - 64, wv = o >> 5;
    part[(size_t)blockIdx.x * 128 + 64 + o] =
        sQf[wv * 32 + (o & 31)] + sQf[(wv + 2) * 32 + (o & 31)];
  }
}

// ---------------------------------------------------------------------------
// kConv1x1m (fp16, LDS-free): A-fragments loaded directly from global.
// ---------------------------------------------------------------------------
__global__ __launch_bounds__(256, 4) void kConv1x1m(
    const unsigned short* __restrict__ wfb, const float* __restrict__ g,
    const float* __restrict__ b, const float* __restrict__ pa,
    const float* __restrict__ stats, float invM,
    const unsigned short* __restrict__ in, unsigned short* __restrict__ outb,
    float* __restrict__ part) {
  __shared__ float scs[64], shs[64];
  __shared__ float sS[4][32], sQ[4][32];
  int tid = threadIdx.x;
  size_t r0 = (size_t)blockIdx.x * 128;
  int l = tid & 63, w = tid >> 6;
  int m = l & 31, kg = l >> 5;

  f16x8 bfr[4];
  const f16x8* bp = (const f16x8*)wfb;
#pragma unroll
  for (int ks = 0; ks < 4; ks++) bfr[ks] = bp[ks * 64 + l];

  if (tid < 64) {
    float mu = stats[tid] * invM;
    float va = fmaxf(stats[64 + tid] * invM - mu * mu, 0.0f);
    float iv = rsqrtf(va + 1e-5f);
    float sc = g[tid] * iv;
    scs[tid] = sc;
    shs[tid] = b[tid] - mu * sc;
  }
  __syncthreads();
  float al = *pa;
  _Float16 alh = (_Float16)al;
  h16x2 a2 = {alh, alh};
  h16x2 z2 = {(_Float16)0.0f, (_Float16)0.0f};
  h16x2 sc2[4][4], sh2[4][4];
#pragma unroll
  for (int ks = 0; ks < 4; ks++)
#pragma unroll
    for (int j = 0; j < 4; j++) {
      int c = ks * 16 + kg * 8 + 2 * j;
      sc2[ks][j] = (h16x2){(_Float16)scs[c], (_Float16)scs[c + 1]};
      sh2[ks][j] = (h16x2){(_Float16)shs[c], (_Float16)shs[c + 1]};
    }

  int rloc = w * 32 + m;
  const f16x8* arow = (const f16x8*)(in + (r0 + rloc) * 64);

#define Z16 {0.f,0.f,0.f,0.f, 0.f,0.f,0.f,0.f, 0.f,0.f,0.f,0.f, 0.f,0.f,0.f,0.f}
  f32x16 acc = Z16;
#undef Z16
#pragma unroll
  for (int ks = 0; ks < 4; ks++) {
    union { f16x8 v; h16x2 h2[4]; } ui, ua;
    ui.v = arow[ks * 2 + kg];
#pragma unroll
    for (int j = 0; j < 4; j++) {
      h16x2 tv = ui.h2[j] * sc2[ks][j] + sh2[ks][j];
      ua.h2[j] = a2 * __builtin_elementwise_min(tv, z2) +
                 __builtin_elementwise_max(tv, z2);
    }
    acc = __builtin_amdgcn_mfma_f32_32x32x16_f16(ua.v, bfr[ks], acc, 0, 0, 0);
  }

  float ss = 0.f, qq = 0.f;
#pragma unroll
  for (int rr = 0; rr < 16; rr++) {
    int rowt = (rr & 3) + ((rr >> 2) << 3) + (kg << 2);
    float v = acc[rr];
    outb[(r0 + (size_t)w * 32 + rowt) * 32 + m] = f2h(v);
    ss += v; qq += v * v;
  }
  ss += __shfl_xor(ss, 32);
  qq += __shfl_xor(qq, 32);
  if (l < 32) { sS[w][l] = ss; sQ[w][l] = qq; }
  __syncthreads();
  if (tid < 32) {
    part[(size_t)blockIdx.x * 64 + tid] = sS[0][tid] + sS[1][tid] + sS[2][tid] + sS[3][tid];
  } else if (tid < 64) {
    int o = tid - 32;
    part[(size_t)blockIdx.x * 64 + 32 + o] = sQ[0][o] + sQ[1][o] + sQ[2][o] + sQ[3][o];
  }
}

// ---------------------------------------------------------------------------
// kConv3m (fp16): LDS staging (9x reuse) unchanged.
// ---------------------------------------------------------------------------
__global__ __launch_bounds__(256, 3) void kConv3m(
    const unsigned short* __restrict__ wf3, const float* __restrict__ g,
    const float* __restrict__ b, const float* __restrict__ pa,
    const float* __restrict__ stats, const unsigned short* __restrict__ in,
    unsigned short* __restrict__ outb, float* __restrict__ part) {
  __shared__ __align__(16) unsigned short h2t[169 * 32];
  __shared__ float scs[32], shs[32];
  __shared__ float sS[4][32], sQ[4][32];
  int tid = threadIdx.x;
  int n = blockIdx.x;
  int l = tid & 63, w = tid >> 6;
  int nt = w & 1, mt = w >> 1;
  int m = l & 31, kg = l >> 5;

  f16x8 bfr[18];
  const f16x8* wfp = (const f16x8*)wf3;
#pragma unroll
  for (int s = 0; s < 18; s++) bfr[s] = wfp[(s * 2 + nt) * 64 + l];

  if (tid < 32) {
    const float invM = 1.0f / 692224.0f;
    float mu = stats[tid] * invM;
    float va = fmaxf(stats[32 + tid] * invM - mu * mu, 0.0f);
    float iv = rsqrtf(va + 1e-5f);
    float sc = g[tid] * iv;
    scs[tid] = sc;
    shs[tid] = b[tid] - mu * sc;
  }
  __syncthreads();
  float al = *pa;
  _Float16 alh = (_Float16)al;
  h16x2 a2 = {alh, alh};
  h16x2 z2 = {(_Float16)0.0f, (_Float16)0.0f};
  int q0 = tid & 3;
  h16x2 sc2[4], sh2[4];
#pragma unroll
  for (int j = 0; j < 4; j++) {
    int c = q0 * 8 + 2 * j;
    sc2[j] = (h16x2){(_Float16)scs[c], (_Float16)scs[c + 1]};
    sh2[j] = (h16x2){(_Float16)shs[c], (_Float16)shs[c + 1]};
  }
  char* hb = (char*)h2t;
  for (int e = tid; e < 676; e += 256) {
    int p = e >> 2;
    union { f16x8 v; h16x2 h2[4]; } u, o8;
    u.v = ((const f16x8*)(in + ((size_t)n * 169 + p) * 32))[q0];
#pragma unroll
    for (int j = 0; j < 4; j++) {
      h16x2 tv = u.h2[j] * sc2[j] + sh2[j];
      o8.h2[j] = a2 * __builtin_elementwise_min(tv, z2) +
                 __builtin_elementwise_max(tv, z2);
    }
    int ad = ((p << 6) + q0 * 16) ^ (((p >> 1) & 7) << 4);
    *(f16x8*)(hb + ad) = o8.v;
  }
  __syncthreads();

  int p = mt * 32 + m;
  p = p > 35 ? 35 : p;
  int pixb = (p / 6) * 26 + (p % 6) * 2;

#define Z16 {0.f,0.f,0.f,0.f, 0.f,0.f,0.f,0.f, 0.f,0.f,0.f,0.f, 0.f,0.f,0.f,0.f}
  f32x16 acc = Z16;
#undef Z16
#pragma unroll
  for (int s = 0; s < 18; s++) {
    int tap = s >> 1;
    int pix = pixb + (tap / 3) * 13 + (tap % 3);
    int ad = ((pix << 6) + (s & 1) * 32 + kg * 16) ^ (((pix >> 1) & 7) << 4);
    f16x8 a = *(const f16x8*)(hb + ad);
    acc = __builtin_amdgcn_mfma_f32_32x32x16_f16(a, bfr[s], acc, 0, 0, 0);
  }

  float ss = 0.f, qq = 0.f;
  int och = nt * 32 + m;
#pragma unroll
  for (int r = 0; r < 16; r++) {
    int row = (r & 3) + ((r >> 2) << 3) + (kg << 2);
    int pp = mt * 32 + row;
    if (pp < 36) {
      float v = acc[r];
      outb[((size_t)n * 36 + pp) * 64 + och] = f2h(v);
      ss += v; qq += v * v;
    }
  }
  ss += __shfl_xor(ss, 32);
  qq += __shfl_xor(qq, 32);
  if (l < 32) { sS[w][l] = ss; sQ[w][l] = qq; }
  __syncthreads();
  if (tid < 64) {
    int o = tid, wv = o >> 5;
    part[(size_t)n * 128 + o] = sS[wv][o & 31] + sS[wv + 2][o & 31];
  } else if (tid < 128) {
    int o = tid - 64, wv = o >> 5;
    part[(size_t)n * 128 + 64 + o] = sQ[wv][o & 31] + sQ[wv + 2][o & 31];
  }
}

// ---------------------------------------------------------------------------
// kConv5m (fp16): y5 out fp16 k-order [n][och*16+p].
// ---------------------------------------------------------------------------
__global__ __launch_bounds__(128) void kConv5m(
    const unsigned short* __restrict__ wf5, const float* __restrict__ g,
    const float* __restrict__ b, const float* __restrict__ pa,
    const float* __restrict__ stats, const unsigned short* __restrict__ in,
    unsigned short* __restrict__ outb, float* __restrict__ part) {
  __shared__ __align__(16) unsigned short h4t[2 * 1280];
  __shared__ float scs[32], shs[32];
  int tid = threadIdx.x;
  int nA = blockIdx.x * 2;
  int l = tid & 63, w = tid >> 6;
  int m = l & 31, kg = l >> 5;

  f16x8 bfr[18];
  const f16x8* wfp = (const f16x8*)wf5;
#pragma unroll
  for (int s = 0; s < 18; s++) bfr[s] = wfp[(s * 2 + w) * 64 + l];

  if (tid < 32) {
    const float invM = 1.0f / 147456.0f;
    float mu = stats[tid] * invM;
    float va = fmaxf(stats[32 + tid] * invM - mu * mu, 0.0f);
    float iv = rsqrtf(va + 1e-5f);
    float sc = g[tid] * iv;
    scs[tid] = sc;
    shs[tid] = b[tid] - mu * sc;
  }
  __syncthreads();
  float al = *pa;
  _Float16 alh = (_Float16)al;
  h16x2 a2 = {alh, alh};
  h16x2 z2 = {(_Float16)0.0f, (_Float16)0.0f};
  int q0 = tid & 3;
  h16x2 sc2[4], sh2[4];
#pragma unroll
  for (int j = 0; j < 4; j++) {
    int c = q0 * 8 + 2 * j;
    sc2[j] = (h16x2){(_Float16)scs[c], (_Float16)scs[c + 1]};
    sh2[j] = (h16x2){(_Float16)shs[c], (_Float16)shs[c + 1]};
  }
  char* hb = (char*)h4t;
  for (int e = tid; e < 288; e += 128) {
    int img = e >= 144;
    int rem = e - img * 144;
    int p = rem >> 2;
    union { f16x8 v; h16x2 h2[4]; } u, o8;
    u.v = ((const f16x8*)(in + ((size_t)(nA + img) * 36 + p) * 32))[q0];
#pragma unroll
    for (int j = 0; j < 4; j++) {
      h16x2 tv = u.h2[j] * sc2[j] + sh2[j];
      o8.h2[j] = a2 * __builtin_elementwise_min(tv, z2) +
                 __builtin_elementwise_max(tv, z2);
    }
    int ad = img * 2560 + (((p << 6) + q0 * 16) ^ (((p >> 1) & 7) << 4));
    *(f16x8*)(hb + ad) = o8.v;
  }
  __syncthreads();

  int imgl = m >> 4;
  int pl = m & 15;
  int pixb = (pl >> 2) * 6 + (pl & 3);
  int ibase = imgl * 2560;

#define Z16 {0.f,0.f,0.f,0.f, 0.f,0.f,0.f,0.f, 0.f,0.f,0.f,0.f, 0.f,0.f,0.f,0.f}
  f32x16 acc = Z16;
#undef Z16
#pragma unroll
  for (int s = 0; s < 18; s++) {
    int tap = s >> 1;
    int pix = pixb + (tap / 3) * 6 + (tap % 3);
    int ad = ibase + (((pix << 6) + (s & 1) * 32 + kg * 16) ^ (((pix >> 1) & 7) << 4));
    f16x8 a = *(const f16x8*)(hb + ad);
    acc = __builtin_amdgcn_mfma_f32_32x32x16_f16(a, bfr[s], acc, 0, 0, 0);
  }

  float ss = 0.f, qq = 0.f;
  int och = w * 32 + m;
#pragma unroll
  for (int r = 0; r < 16; r++) {
    int row = (r & 3) + ((r >> 2) << 3) + (kg << 2);
    int img = row >> 4, p = row & 15;
    float v = acc[r];
    outb[(size_t)(nA + img) * 1024 + och * 16 + p] = f2h(v);
    ss += v; qq += v * v;
  }
  ss += __shfl_xor(ss, 32);
  qq += __shfl_xor(qq, 32);
  if (l < 32) {
    part[(size_t)blockIdx.x * 128 + w * 32 + l] = ss;
    part[(size_t)blockIdx.x * 128 + 64 + w * 32 + l] = qq;
  }
}

// ---------------------------------------------------------------------------
// kFC1m (fp16, LDS-free): grid 256 = (nb, f-half).
// ---------------------------------------------------------------------------
__global__ __launch_bounds__(128) void kFC1m(
    const unsigned short* __restrict__ wfl, const float* __restrict__ g,
    const float* __restrict__ b, const float* __restrict__ pa,
    const float* __restrict__ stats, const unsigned short* __restrict__ y5,
    float* __restrict__ z, float* __restrict__ part) {
  __shared__ float scs[64], shs[64];
  int tid = threadIdx.x;
  int nb = blockIdx.x >> 1, fh = blockIdx.x & 1;
  int n0 = nb * 32;
  int l = tid & 63, w = tid >> 6;
  int m = l & 31, kg = l >> 5;
  if (tid < 64) {
    const float invM = 1.0f / 65536.0f;
    float mu = stats[tid] * invM;
    float va = fmaxf(stats[64 + tid] * invM - mu * mu, 0.0f);
    float iv = rsqrtf(va + 1e-5f);
    float sc = g[tid] * iv;
    scs[tid] = sc;
    shs[tid] = b[tid] - mu * sc;
  }
  __syncthreads();
  float al = *pa;
  _Float16 alh = (_Float16)al;
  h16x2 a2 = {alh, alh};
  h16x2 z2 = {(_Float16)0.0f, (_Float16)0.0f};
  int t = fh * 2 + w;
  const f16x8* bp = (const f16x8*)wfl;
  const f16x8* arow = (const f16x8*)(y5 + (size_t)(n0 + m) * 1024);

#define Z16 {0.f,0.f,0.f,0.f, 0.f,0.f,0.f,0.f, 0.f,0.f,0.f,0.f, 0.f,0.f,0.f,0.f}
  f32x16 acc = Z16;
#undef Z16
#pragma unroll 4
  for (int ks = 0; ks < 64; ks++) {
    _Float16 sch = (_Float16)scs[ks];
    _Float16 shh = (_Float16)shs[ks];
    h16x2 sc2 = {sch, sch};
    h16x2 sh2 = {shh, shh};
    union { f16x8 v; h16x2 h2[4]; } ui, ua;
    ui.v = arow[ks * 2 + kg];
#pragma unroll
    for (int j = 0; j < 4; j++) {
      h16x2 tv = ui.h2[j] * sc2 + sh2;
      ua.h2[j] = a2 * __builtin_elementwise_min(tv, z2) +
                 __builtin_elementwise_max(tv, z2);
    }
    f16x8 bv = bp[(ks * 4 + t) * 64 + l];
    acc = __builtin_amdgcn_mfma_f32_32x32x16_f16(ua.v, bv, acc, 0, 0, 0);
  }

  float s0 = 0.f, q0 = 0.f;
  int f = fh * 64 + w * 32 + m;
#pragma unroll
  for (int r = 0; r < 16; r++) {
    int n = (r & 3) + ((r >> 2) << 3) + (kg << 2);
    float v = acc[r];
    z[(size_t)(n0 + n) * 128 + f] = v;
    s0 += v; q0 += v * v;
  }
  s0 += __shfl_xor(s0, 32);
  q0 += __shfl_xor(q0, 32);
  if (l < 32) {
    size_t base = (size_t)nb * 256;
    part[base + fh * 64 + w * 32 + l] = s0;
    part[base + 128 + fh * 64 + w * 32 + l] = q0;
  }
}

// ---------------------------------------------------------------------------
__global__ __launch_bounds__(256) void kFC2Arc(
    const float* __restrict__ z, const float* __restrict__ s6,
    const float* __restrict__ lg1, const float* __restrict__ lb1,
    const float* __restrict__ pl1, const float* __restrict__ lw2,
    const float* __restrict__ lb2, const float* __restrict__ aw,
    const int* __restrict__ labels, float* __restrict__ out,
    float* __restrict__ lpart) {
  __shared__ float scz[128], shz[128], w2a[128], w2b[128];
  __shared__ float awl[20];
  __shared__ float lred[4];
  int tid = threadIdx.x;
  if (tid < 128) {
    const float invM = 1.0f / 4096.0f;
    float mu = s6[tid] * invM;
    float va = fmaxf(s6[128 + tid] * invM - mu * mu, 0.0f);
    float iv = rsqrtf(va + 1e-5f);
    float sc = lg1[tid] * iv;
    scz[tid] = sc;
    shz[tid] = lb1[tid] - mu * sc;
    w2a[tid] = lw2[tid];
    w2b[tid] = lw2[128 + tid];
  }
  if (tid < 20) awl[tid] = aw[tid];
  __syncthreads();
  float al = *pl1;
  int n = blockIdx.x * 256 + tid;
  const float4* zr = (const float4*)(z + (size_t)n * 128);
  float f0 = lb2[0], f1 = lb2[1];
#pragma unroll
  for (int kb = 0; kb < 32; kb++) {
    float4 v = zr[kb];
    float hv[4] = {v.x, v.y, v.z, v.w};
#pragma unroll
    for (int u = 0; u < 4; u++) {
      int k = kb * 4 + u;
      float h = fmaf(hv[u], scz[k], shz[k]);
      h = h > 0.f ? h : al * h;
      f0 = fmaf(h, w2a[k], f0);
      f1 = fmaf(h, w2b[k], f1);
    }
  }
  out[(size_t)n * 2] = f0;
  out[(size_t)n * 2 + 1] = f1;
  float nrm = sqrtf(fmaxf(f0 * f0 + f1 * f1, 1e-30f));
  float xn0 = f0 / nrm, xn1 = f1 / nrm;
  int lab = labels[n];
  float wv[10];
  float m64 = -3.4e38f;
#pragma unroll
  for (int j = 0; j < 10; j++) {
    float w = xn0 * awl[2 * j] + xn1 * awl[2 * j + 1];
    wv[j] = w;
    out[8192 + (size_t)n * 10 + j] = w;
    m64 = fmaxf(m64, 64.0f * w);
  }
  float tgt = wv[0];
#pragma unroll
  for (int j = 1; j < 10; j++) if (j == lab) tgt = wv[j];
  if (lab == 0) tgt = wv[0];
  const float CLO = (float)(-1.0 + 1e-7);
  const float CHI = (float)(1.0 - 1e-7);
  float t = fminf(fmaxf(tgt, CLO), CHI);
  float num = 64.0f * (t * 0.87758256189037276f - 0.47942553860420301f * sqrtf(fmaxf(1.0f - t * t, 0.0f)));
  float L = fmaxf(num, m64);
  float dsum = expf(num - L) - expf(64.0f * tgt - L);
#pragma unroll
  for (int j = 0; j < 10; j++) dsum += expf(64.0f * wv[j] - L);
  dsum = fmaxf(dsum, 1e-30f);
  float li = num - (L + logf(dsum));
#pragma unroll
  for (int off = 32; off; off >>= 1) li += __shfl_down(li, off);
  if ((tid & 63) == 0) lred[tid >> 6] = li;
  __syncthreads();
  if (tid == 0) lpart[blockIdx.x] = lred[0] + lred[1] + lred[2] + lred[3];
}

__global__ void kFinal(const float* __restrict__ lpart, float* __restrict__ out) {
  int tid = threadIdx.x;
  float v = (tid < 16) ? lpart[tid] : 0.f;
#pragma unroll
  for (int off = 8; off; off >>= 1) v += __shfl_down(v, off);
  if (tid == 0) out[49152] = -v * (1.0f / 4096.0f);
}

// ---------------------------------------------------------------------------
extern "C" void kernel_launch(void* const* d_in, const int* in_sizes, int n_in,
                              void* d_out, int out_size, void* d_ws, size_t ws_size,
                              hipStream_t stream) {
  const float* x   = (const float*)d_in[0];
  const int* labels = (const int*)d_in[1];
  const float* cw0 = (const float*)d_in[2];
  const float* bg0 = (const float*)d_in[3];
  const float* bb0 = (const float*)d_in[4];
  const float* pa0 = (const float*)d_in[5];
  const float* cw1 = (const float*)d_in[6];
  const float* bg1 = (const float*)d_in[7];
  const float* bb1 = (const float*)d_in[8];
  const float* pa1 = (const float*)d_in[9];
  const float* cw2 = (const float*)d_in[10];
  const float* bg2 = (const float*)d_in[11];
  const float* bb2 = (const float*)d_in[12];
  const float* pa2 = (const float*)d_in[13];
  const float* cw3 = (const float*)d_in[14];
  const float* bg3 = (const float*)d_in[15];
  const float* bb3 = (const float*)d_in[16];
  const float* pa3 = (const float*)d_in[17];
  const float* cw4 = (const float*)d_in[18];
  const float* bg4 = (const float*)d_in[19];
  const float* bb4 = (const float*)d_in[20];
  const float* pa4 = (const float*)d_in[21];
  const float* cw5 = (const float*)d_in[22];
  const float* bg5 = (const float*)d_in[23];
  const float* bb5 = (const float*)d_in[24];
  const float* pa5 = (const float*)d_in[25];
  const float* lw1 = (const float*)d_in[26];
  const float* lg1 = (const float*)d_in[27];
  const float* lb1 = (const float*)d_in[28];
  const float* pl1 = (const float*)d_in[29];
  const float* lw2 = (const float*)d_in[30];
  const float* lb2 = (const float*)d_in[31];
  const float* aw  = (const float*)d_in[32];
  float* out = (float*)d_out;
  float* ws = (float*)d_ws;

  float* PX = ws;                    // 1024
  float* SX = ws + 1024;             // 2
  float* S1 = ws + 1040;             // 128
  float* S2 = ws + 1168;             // 64
  float* S3 = ws + 1232;             // 128
  float* S4 = ws + 1360;             // 64
  float* S5 = ws + 1424;             // 128
  float* S6 = ws + 1552;             // 256
  float* LP = ws + 1808;             // 16
  float* P1 = ws + 2048;             // [8192][128] = 1048576
  float* P2 = P1 + 1048576;          // [5408][64]  = 346112
  float* P3 = P2 + 346112;           // [4096][128] = 524288
  float* P4 = P3 + 524288;           // [1152][64]  = 73728
  float* P5 = P4 + 73728;            // [2048][128] = 262144
  float* P6 = P1;                    // [128][256] — aliases dead P1
  unsigned short* Y1 = (unsigned short*)(ws + (size_t)2359296);  // [4096][169][64] fp16
  unsigned short* Y2 = Y1 + (size_t)44302336;  // [4096][169][32] fp16
  unsigned short* Y3 = Y2 + (size_t)22151168;  // [4096][36][64] fp16
  unsigned short* Y4 = Y3 + (size_t)9437184;   // [4096][36][32] fp16
  unsigned short* Y5 = Y4 + (size_t)4718592;   // [4096][1024] fp16 k-order
  float* Z  = (float*)(Y5 + (size_t)4194304);  // [4096][128] fp32
  float* WF = Z + 524288;            // conv1 weight frags (fp16)
  float* WFL = WF + 16384;           // lw1 frags (fp16)
  float* WF3 = WFL + 65536;          // conv3 weight frags (fp16)
  float* WC2 = WF3 + 16384;          // conv2 1x1 frags (fp16)
  float* WC4 = WC2 + 1024;           // conv4 1x1 frags (fp16)
  float* WF5 = WC4 + 1024;           // conv5 weight frags (fp16)

  kSetup<<<533, 256, 0, stream>>>(x, PX, cw1, (unsigned short*)WF,
                                  cw3, (unsigned short*)WF3,
                                  cw5, (unsigned short*)WF5,
                                  cw2, (unsigned short*)WC2,
                                  cw4, (unsigned short*)WC4,
                                  lw1, (unsigned short*)WFL);
  kRedPart<<<2, 256, 0, stream>>>(PX, SX, 512, 2);
  kConv1<<<8192, 256, 0, stream>>>(x, cw0, bg0, bb0, pa0, (const unsigned short*)WF,
                                   SX, Y1, P1);
  kRedPart<<<128, 256, 0, stream>>>(P1, S1, 8192, 128);
  kConv1x1m<<<5408, 256, 0, stream>>>((const unsigned short*)WC2, bg1, bb1, pa1, S1,
                                      1.0f / 692224.0f, Y1, Y2, P2);
  kRedPart<<<64, 256, 0, stream>>>(P2, S2, 5408, 64);
  kConv3m<<<4096, 256, 0, stream>>>((const unsigned short*)WF3, bg2, bb2, pa2, S2, Y2, Y3, P3);
  kRedPart<<<128, 256, 0, stream>>>(P3, S3, 4096, 128);
  kConv1x1m<<<1152, 256, 0, stream>>>((const unsigned short*)WC4, bg3, bb3, pa3, S3,
                                      1.0f / 147456.0f, Y3, Y4, P4);
  kRedPart<<<64, 256, 0, stream>>>(P4, S4, 1152, 64);
  kConv5m<<<2048, 128, 0, stream>>>((const unsigned short*)WF5, bg4, bb4, pa4, S4, Y4, Y5, P5);
  kRedPart<<<128, 256, 0, stream>>>(P5, S5, 2048, 128);
  kFC1m<<<256, 128, 0, stream>>>((const unsigned short*)WFL, bg5, bb5, pa5, S5, Y5, Z, P6);
  kRedPart<<<256, 256, 0, stream>>>(P6, S6, 128, 256);
  kFC2Arc<<<16, 256, 0, stream>>>(Z, S6, lg1, lb1, pl1, lw2, lb2, aw, labels, out, LP);
  kFinal<<<1, 64, 0, stream>>>(LP, out);
}